// Round 5
// baseline (271.607 us; speedup 1.0000x reference)
//
#include <hip/hip_runtime.h>

#define NV 6890
#define NJ 24
#define BATCH 512
#define NCOL 20670   // NV*3
#define NCOLP 20736  // padded to 192*108
#define KK 224       // 207 pose + 10 beta + 7 zero
#define JCH 864      // vert chunk for jreg stage A (8*864 >= 6890)
#define NCOLT 192    // cols per block (= 64 verts)
#define MT 32        // batches per block
#define LSTR 193     // LDS row stride (floats)

typedef float f4 __attribute__((ext_vector_type(4)));
typedef float f32x4 __attribute__((ext_vector_type(4)));
typedef short bf16x8 __attribute__((ext_vector_type(8)));
typedef unsigned short ushort8 __attribute__((ext_vector_type(8)));

// ws layout:
//   Abuf  ushort[512][224]     @ 0
//   Bbuf  ushort[20736][224]   @ 229376
//   Amat  float[512][24][12]   @ 9519104
//   JSp   float[24][33]        @ 10108928
//   part  float[24][8][33]     @ 10112096

__device__ __forceinline__ ushort bf16_rne(float x) {
  union { float f; unsigned u; } c; c.f = x;
  unsigned r = c.u + 0x7fffu + ((c.u >> 16) & 1u);
  return (ushort)(r >> 16);
}

// ---------------- K0a: partial JS reduction, grid (24, 8) ----------------
__global__ void k_jregA(const float* __restrict__ Jreg, const float* __restrict__ vtemp,
                        const float* __restrict__ sdirs, float* __restrict__ partial) {
  int j = blockIdx.x, bz = blockIdx.y;
  int tid = threadIdx.x;
  float acc[33];
#pragma unroll
  for (int i = 0; i < 33; ++i) acc[i] = 0.f;
  int v0 = bz * JCH;
  int v1 = v0 + JCH; if (v1 > NV) v1 = NV;
  for (int v = v0 + tid; v < v1; v += 256) {
    float w = Jreg[(size_t)j * NV + v];
    const float* vt = vtemp + (size_t)v * 3;
    acc[0] += w * vt[0]; acc[1] += w * vt[1]; acc[2] += w * vt[2];
    const float* sdv = sdirs + (size_t)v * 30;
#pragma unroll
    for (int t = 0; t < 30; ++t) acc[3 + t] += w * sdv[t];
  }
#pragma unroll
  for (int i = 0; i < 33; ++i) {
    float a = acc[i];
#pragma unroll
    for (int s = 32; s > 0; s >>= 1) a += __shfl_xor(a, s, 64);
    acc[i] = a;
  }
  __shared__ float red[4][34];
  int lane = tid & 63, wv = tid >> 6;
  if (lane == 0) {
#pragma unroll
    for (int i = 0; i < 33; ++i) red[wv][i] = acc[i];
  }
  __syncthreads();
  if (tid < 33) {
    float s = red[0][tid] + red[1][tid] + red[2][tid] + red[3][tid];
    partial[((size_t)j * 8 + bz) * 33 + tid] = s;
  }
}

// ---------------- K0b: sum the 8 partials ----------------
__global__ void k_jregB(const float* __restrict__ partial, float* __restrict__ JSp) {
  int i = blockIdx.x * 256 + threadIdx.x;
  if (i < NJ * 33) {
    int j = i / 33, q = i % 33;
    float s = 0.f;
#pragma unroll
    for (int bz = 0; bz < 8; ++bz) s += partial[((size_t)j * 8 + bz) * 33 + q];
    JSp[i] = s;
  }
}

// ---------------- K1: per-batch joints, rodrigues, chain, A matrices, Abuf ----------------
__global__ void k_batch(const float* __restrict__ pose, const float* __restrict__ beta,
                        const int* __restrict__ parent, const float* __restrict__ JSp,
                        ushort* __restrict__ Abuf, float* __restrict__ Amat) {
  int b = blockIdx.x;
  int j = threadIdx.x;  // 64 threads
  __shared__ float jl[NJ][3];
  __shared__ float gl[NJ][16];

  float bt[10];
#pragma unroll
  for (int t = 0; t < 10; ++t) bt[t] = beta[b * 10 + t];

  float R[9];
  float Jj[3] = {0.f, 0.f, 0.f};
  if (j < NJ) {
    const float* js = JSp + j * 33;
#pragma unroll
    for (int c = 0; c < 3; ++c) {
      float a = js[c];
#pragma unroll
      for (int t = 0; t < 10; ++t) a += js[3 + c * 10 + t] * bt[t];
      Jj[c] = a;
      jl[j][c] = a;
    }
    float rx = pose[b * 72 + j * 3 + 0];
    float ry = pose[b * 72 + j * 3 + 1];
    float rz = pose[b * 72 + j * 3 + 2];
    float theta = sqrtf(rx * rx + ry * ry + rz * rz) + 1e-8f;
    float inv = 1.f / theta;
    float ax = rx * inv, ay = ry * inv, az = rz * inv;
    float c = cosf(theta), s = sinf(theta), oc = 1.f - c;
    R[0] = c + oc * ax * ax;      R[1] = oc * ax * ay - s * az; R[2] = oc * ax * az + s * ay;
    R[3] = oc * ax * ay + s * az; R[4] = c + oc * ay * ay;      R[5] = oc * ay * az - s * ax;
    R[6] = oc * ax * az - s * ay; R[7] = oc * ay * az + s * ax; R[8] = c + oc * az * az;
  }
  __syncthreads();

  // Abuf cols: 0..206 lrotmin, 207..216 beta, 217..223 zero (bf16)
  if (j >= 1 && j < NJ) {
    ushort* lr = Abuf + b * KK + (j - 1) * 9;
#pragma unroll
    for (int k = 0; k < 9; ++k)
      lr[k] = bf16_rne(R[k] - ((k == 0 || k == 4 || k == 8) ? 1.f : 0.f));
  }
  if (j >= 32 && j < 42) Abuf[b * KK + 207 + (j - 32)] = bf16_rne(bt[j - 32]);
  if (j >= 42 && j < 49) Abuf[b * KK + 207 + (j - 32)] = 0;

  if (j < NJ) {
    int par = (j == 0) ? 0 : parent[j - 1];
#pragma unroll
    for (int r = 0; r < 3; ++r) {
      gl[j][r * 4 + 0] = R[r * 3 + 0];
      gl[j][r * 4 + 1] = R[r * 3 + 1];
      gl[j][r * 4 + 2] = R[r * 3 + 2];
      gl[j][r * 4 + 3] = (j == 0) ? Jj[r] : Jj[r] - jl[par][r];
    }
  }
  __syncthreads();

  if (j < NJ) {
    int a[12];
    int n = 0, cur = j;
    while (cur != 0 && n < 12) { a[n++] = cur; cur = parent[cur - 1]; }
    float G[12];
#pragma unroll
    for (int r = 0; r < 3; ++r)
#pragma unroll
      for (int cc = 0; cc < 4; ++cc) G[r * 4 + cc] = gl[0][r * 4 + cc];
    for (int i = n - 1; i >= 0; --i) {
      const float* L = gl[a[i]];
      float C[12];
#pragma unroll
      for (int r = 0; r < 3; ++r) {
#pragma unroll
        for (int cc = 0; cc < 4; ++cc) {
          float sacc = (cc == 3) ? G[r * 4 + 3] : 0.f;
#pragma unroll
          for (int k = 0; k < 3; ++k) sacc += G[r * 4 + k] * L[k * 4 + cc];
          C[r * 4 + cc] = sacc;
        }
      }
#pragma unroll
      for (int k = 0; k < 12; ++k) G[k] = C[k];
    }
    float* A = Amat + b * 288 + j * 12;
#pragma unroll
    for (int r = 0; r < 3; ++r) {
      A[r * 4 + 0] = G[r * 4 + 0];
      A[r * 4 + 1] = G[r * 4 + 1];
      A[r * 4 + 2] = G[r * 4 + 2];
      A[r * 4 + 3] = G[r * 4 + 3] -
                     (G[r * 4 + 0] * jl[j][0] + G[r * 4 + 1] * jl[j][1] + G[r * 4 + 2] * jl[j][2]);
    }
  }
}

// ---------------- K2: B prep  Bbuf[n][k]: 0..206 posedirs, 207..216 shapedirs, rest 0 ----------------
__global__ void k_prepb(const float* __restrict__ pdirs, const float* __restrict__ sdirs,
                        ushort* __restrict__ Bbuf) {
  int idx = blockIdx.x * 256 + threadIdx.x;  // NCOLP*28
  int n = idx / 28, k8 = idx % 28;
  int kbase = k8 * 8;
  ushort8 o;
#pragma unroll
  for (int e = 0; e < 8; ++e) {
    int k = kbase + e;
    float v = 0.f;
    if (n < NCOL) {
      if (k < 207) v = pdirs[(size_t)n * 207 + k];
      else if (k < 217) v = sdirs[(size_t)n * 10 + (k - 207)];
    }
    o[e] = bf16_rne(v);
  }
  *(ushort8*)(Bbuf + (size_t)n * KK + kbase) = o;
}

// ---------------- K3: fused MFMA pose-blend GEMM + skinning ----------------
// grid (NCOLP/192, BATCH/32), 256 threads.
// Phase 1: v_posed tile (32 batches x 192 cols) via MFMA into LDS.
// Phase 2: per-thread skinning (1 vert x 8 batches), A via scalar loads.
__launch_bounds__(256)
__global__ void k_gemmskin(const ushort* __restrict__ Abuf, const ushort* __restrict__ Bbuf,
                           const float* __restrict__ vtemp, const float* __restrict__ wgt,
                           const float* __restrict__ Amat, float* __restrict__ out) {
  __shared__ float vp_lds[MT * LSTR];  // 24704 B

  int tid = threadIdx.x;
  int wid = tid >> 6, lane = tid & 63;
  int lo = lane & 15, hi = lane >> 4;
  int n0 = blockIdx.x * NCOLT;
  int m0 = blockIdx.y * MT;

  // ---- Phase 1: GEMM ----
  bf16x8 Af[2][7];
#pragma unroll
  for (int mt = 0; mt < 2; ++mt) {
    const ushort* arow = Abuf + (size_t)(m0 + mt * 16 + lo) * KK + hi * 8;
#pragma unroll
    for (int kc = 0; kc < 7; ++kc)
      Af[mt][kc] = *(const bf16x8*)(arow + kc * 32);
  }

#pragma unroll
  for (int s = 0; s < 3; ++s) {
    int cb = wid * 48 + s * 16;  // local col base of this strip
    const ushort* brow = Bbuf + (size_t)(n0 + cb + lo) * KK + hi * 8;
    bf16x8 Bf[7];
#pragma unroll
    for (int kc = 0; kc < 7; ++kc)
      Bf[kc] = *(const bf16x8*)(brow + kc * 32);
    int gc = n0 + cb + lo;
    float vt = (gc < NCOL) ? vtemp[gc] : 0.f;
#pragma unroll
    for (int mt = 0; mt < 2; ++mt) {
      f32x4 acc = {vt, vt, vt, vt};
#pragma unroll
      for (int kc = 0; kc < 7; ++kc)
        acc = __builtin_amdgcn_mfma_f32_16x16x32_bf16(Af[mt][kc], Bf[kc], acc, 0, 0, 0);
#pragma unroll
      for (int r = 0; r < 4; ++r)
        vp_lds[(mt * 16 + hi * 4 + r) * LSTR + cb + lo] = acc[r];
    }
  }
  __syncthreads();

  // ---- Phase 2: skinning ----
  int v_loc = tid & 63;
  int bg = __builtin_amdgcn_readfirstlane(tid >> 6);  // wave-uniform
  int vg = n0 / 3 + v_loc;
  bool vok = vg < NV;

  float w[24];
  if (vok) {
    const f4* wp = (const f4*)(wgt + (size_t)vg * 24);
#pragma unroll
    for (int q = 0; q < 6; ++q) {
      f4 t = wp[q];
      w[q * 4 + 0] = t.x; w[q * 4 + 1] = t.y; w[q * 4 + 2] = t.z; w[q * 4 + 3] = t.w;
    }
  } else {
#pragma unroll
    for (int q = 0; q < 24; ++q) w[q] = 0.f;
  }

  const float* Abase = Amat + (size_t)(m0 + bg * 8) * 288;  // wave-uniform

#pragma unroll
  for (int pp = 0; pp < 4; ++pp) {  // 2 batches per iteration
    const float* A0 = Abase + pp * 2 * 288;
    float T[2][12];
#pragma unroll
    for (int e = 0; e < 2; ++e)
#pragma unroll
      for (int q = 0; q < 12; ++q) T[e][q] = 0.f;
#pragma unroll
    for (int j = 0; j < NJ; ++j) {
      float wv = w[j];
#pragma unroll
      for (int q = 0; q < 12; ++q) {
        T[0][q] += wv * A0[j * 12 + q];
        T[1][q] += wv * A0[288 + j * 12 + q];
      }
    }
#pragma unroll
    for (int e = 0; e < 2; ++e) {
      int lb = bg * 8 + pp * 2 + e;
      float x = vp_lds[lb * LSTR + v_loc * 3 + 0];
      float y = vp_lds[lb * LSTR + v_loc * 3 + 1];
      float z = vp_lds[lb * LSTR + v_loc * 3 + 2];
      if (vok) {
        float* o = out + ((size_t)(m0 + lb) * NV + vg) * 3;
        o[0] = T[e][0] * x + T[e][1] * y + T[e][2]  * z + T[e][3];
        o[1] = T[e][4] * x + T[e][5] * y + T[e][6]  * z + T[e][7];
        o[2] = T[e][8] * x + T[e][9] * y + T[e][10] * z + T[e][11];
      }
    }
  }
}

extern "C" void kernel_launch(void* const* d_in, const int* in_sizes, int n_in,
                              void* d_out, int out_size, void* d_ws, size_t ws_size,
                              hipStream_t stream) {
  const float* pose   = (const float*)d_in[0];
  const float* beta   = (const float*)d_in[1];
  const float* vtemp  = (const float*)d_in[2];
  const float* sdirs  = (const float*)d_in[3];
  const float* pdirs  = (const float*)d_in[4];
  const float* Jreg   = (const float*)d_in[5];
  const float* wgt    = (const float*)d_in[6];
  const int*   parent = (const int*)d_in[7];
  float* out = (float*)d_out;

  ushort* Abuf = (ushort*)d_ws;
  ushort* Bbuf = Abuf + (size_t)BATCH * KK;
  float*  Amat = (float*)(Bbuf + (size_t)NCOLP * KK);
  float*  JSp  = Amat + (size_t)BATCH * 288;
  float*  part = JSp + NJ * 33;

  hipLaunchKernelGGL(k_jregA, dim3(NJ, 8), dim3(256), 0, stream, Jreg, vtemp, sdirs, part);
  hipLaunchKernelGGL(k_jregB, dim3(4), dim3(256), 0, stream, part, JSp);
  hipLaunchKernelGGL(k_prepb, dim3((NCOLP * 28) / 256), dim3(256), 0, stream, pdirs, sdirs, Bbuf);
  hipLaunchKernelGGL(k_batch, dim3(BATCH), dim3(64), 0, stream, pose, beta, parent, JSp, Abuf, Amat);
  hipLaunchKernelGGL(k_gemmskin, dim3(NCOLP / NCOLT, BATCH / MT), dim3(256), 0, stream,
                     Abuf, Bbuf, vtemp, wgt, Amat, out);
}

// Round 6
// 103.671 us; speedup vs baseline: 2.6199x; 2.6199x over previous
//
#include <hip/hip_runtime.h>

#define NV 6890
#define NJ 24
#define BATCH 512
#define NCOL 20670   // NV*3
#define NCOLP 20736  // padded to 128*162
#define KK 224       // 207 pose + 10 beta + 7 zero
#define VT 64
#define JCH 864      // vert chunk for jreg stage A (8*864 >= 6890)

typedef float f4 __attribute__((ext_vector_type(4)));
typedef float f32x4 __attribute__((ext_vector_type(4)));
typedef short bf16x8 __attribute__((ext_vector_type(8)));
typedef unsigned short ushort8 __attribute__((ext_vector_type(8)));

// ws layout (bytes):
//   Abuf  ushort[512][224]      @ 0
//   Bbuf  ushort[20736][224]    @ 229376
//   Amat  float[512][24][12]    @ 9519104
//   JSp   float[24][33]         @ 10108928
//   part  float[24][8][33]      @ 10112096
//   vp2   uint[256][20736]      @ 10137600   (bf16-pair packed v_posed; needs ws >= 31371264)
#define VP2_OFF 10137600
#define WS_NEED (VP2_OFF + (size_t)256 * NCOLP * 4)

__device__ __forceinline__ unsigned short bf16_rne(float x) {
  union { float f; unsigned u; } c; c.f = x;
  unsigned r = c.u + 0x7fffu + ((c.u >> 16) & 1u);
  return (unsigned short)(r >> 16);
}
__device__ __forceinline__ float bf16lo_f(unsigned u) {
  union { unsigned u; float f; } c; c.u = u << 16; return c.f;
}
__device__ __forceinline__ float bf16hi_f(unsigned u) {
  union { unsigned u; float f; } c; c.u = u & 0xFFFF0000u; return c.f;
}

// ---------------- K0a: partial JS reduction, grid (24, 8) ----------------
__global__ void k_jregA(const float* __restrict__ Jreg, const float* __restrict__ vtemp,
                        const float* __restrict__ sdirs, float* __restrict__ partial) {
  int j = blockIdx.x, bz = blockIdx.y;
  int tid = threadIdx.x;
  float acc[33];
#pragma unroll
  for (int i = 0; i < 33; ++i) acc[i] = 0.f;
  int v0 = bz * JCH;
  int v1 = v0 + JCH; if (v1 > NV) v1 = NV;
  for (int v = v0 + tid; v < v1; v += 256) {
    float w = Jreg[(size_t)j * NV + v];
    const float* vt = vtemp + (size_t)v * 3;
    acc[0] += w * vt[0]; acc[1] += w * vt[1]; acc[2] += w * vt[2];
    const float* sdv = sdirs + (size_t)v * 30;
#pragma unroll
    for (int t = 0; t < 30; ++t) acc[3 + t] += w * sdv[t];
  }
#pragma unroll
  for (int i = 0; i < 33; ++i) {
    float a = acc[i];
#pragma unroll
    for (int s = 32; s > 0; s >>= 1) a += __shfl_xor(a, s, 64);
    acc[i] = a;
  }
  __shared__ float red[4][34];
  int lane = tid & 63, wv = tid >> 6;
  if (lane == 0) {
#pragma unroll
    for (int i = 0; i < 33; ++i) red[wv][i] = acc[i];
  }
  __syncthreads();
  if (tid < 33) {
    float s = red[0][tid] + red[1][tid] + red[2][tid] + red[3][tid];
    partial[((size_t)j * 8 + bz) * 33 + tid] = s;
  }
}

// ---------------- K0b: sum the 8 partials ----------------
__global__ void k_jregB(const float* __restrict__ partial, float* __restrict__ JSp) {
  int i = blockIdx.x * 256 + threadIdx.x;
  if (i < NJ * 33) {
    int j = i / 33, q = i % 33;
    float s = 0.f;
#pragma unroll
    for (int bz = 0; bz < 8; ++bz) s += partial[((size_t)j * 8 + bz) * 33 + q];
    JSp[i] = s;
  }
}

// ---------------- K1: per-batch joints, rodrigues, chain, A matrices, Abuf ----------------
__global__ void k_batch(const float* __restrict__ pose, const float* __restrict__ beta,
                        const int* __restrict__ parent, const float* __restrict__ JSp,
                        unsigned short* __restrict__ Abuf, float* __restrict__ Amat) {
  int b = blockIdx.x;
  int j = threadIdx.x;  // 64 threads
  __shared__ float jl[NJ][3];
  __shared__ float gl[NJ][16];

  float bt[10];
#pragma unroll
  for (int t = 0; t < 10; ++t) bt[t] = beta[b * 10 + t];

  float R[9];
  float Jj[3] = {0.f, 0.f, 0.f};
  if (j < NJ) {
    const float* js = JSp + j * 33;
#pragma unroll
    for (int c = 0; c < 3; ++c) {
      float a = js[c];
#pragma unroll
      for (int t = 0; t < 10; ++t) a += js[3 + c * 10 + t] * bt[t];
      Jj[c] = a;
      jl[j][c] = a;
    }
    float rx = pose[b * 72 + j * 3 + 0];
    float ry = pose[b * 72 + j * 3 + 1];
    float rz = pose[b * 72 + j * 3 + 2];
    float theta = sqrtf(rx * rx + ry * ry + rz * rz) + 1e-8f;
    float inv = 1.f / theta;
    float ax = rx * inv, ay = ry * inv, az = rz * inv;
    float c = cosf(theta), s = sinf(theta), oc = 1.f - c;
    R[0] = c + oc * ax * ax;      R[1] = oc * ax * ay - s * az; R[2] = oc * ax * az + s * ay;
    R[3] = oc * ax * ay + s * az; R[4] = c + oc * ay * ay;      R[5] = oc * ay * az - s * ax;
    R[6] = oc * ax * az - s * ay; R[7] = oc * ay * az + s * ax; R[8] = c + oc * az * az;
  }
  __syncthreads();

  // Abuf cols: 0..206 lrotmin, 207..216 beta, 217..223 zero (bf16)
  if (j >= 1 && j < NJ) {
    unsigned short* lr = Abuf + b * KK + (j - 1) * 9;
#pragma unroll
    for (int k = 0; k < 9; ++k)
      lr[k] = bf16_rne(R[k] - ((k == 0 || k == 4 || k == 8) ? 1.f : 0.f));
  }
  if (j >= 32 && j < 42) Abuf[b * KK + 207 + (j - 32)] = bf16_rne(bt[j - 32]);
  if (j >= 42 && j < 49) Abuf[b * KK + 207 + (j - 32)] = 0;

  if (j < NJ) {
    int par = (j == 0) ? 0 : parent[j - 1];
#pragma unroll
    for (int r = 0; r < 3; ++r) {
      gl[j][r * 4 + 0] = R[r * 3 + 0];
      gl[j][r * 4 + 1] = R[r * 3 + 1];
      gl[j][r * 4 + 2] = R[r * 3 + 2];
      gl[j][r * 4 + 3] = (j == 0) ? Jj[r] : Jj[r] - jl[par][r];
    }
  }
  __syncthreads();

  if (j < NJ) {
    int a[12];
    int n = 0, cur = j;
    while (cur != 0 && n < 12) { a[n++] = cur; cur = parent[cur - 1]; }
    float G[12];
#pragma unroll
    for (int r = 0; r < 3; ++r)
#pragma unroll
      for (int cc = 0; cc < 4; ++cc) G[r * 4 + cc] = gl[0][r * 4 + cc];
    for (int i = n - 1; i >= 0; --i) {
      const float* L = gl[a[i]];
      float C[12];
#pragma unroll
      for (int r = 0; r < 3; ++r) {
#pragma unroll
        for (int cc = 0; cc < 4; ++cc) {
          float sacc = (cc == 3) ? G[r * 4 + 3] : 0.f;
#pragma unroll
          for (int k = 0; k < 3; ++k) sacc += G[r * 4 + k] * L[k * 4 + cc];
          C[r * 4 + cc] = sacc;
        }
      }
#pragma unroll
      for (int k = 0; k < 12; ++k) G[k] = C[k];
    }
    float* A = Amat + b * 288 + j * 12;
#pragma unroll
    for (int r = 0; r < 3; ++r) {
      A[r * 4 + 0] = G[r * 4 + 0];
      A[r * 4 + 1] = G[r * 4 + 1];
      A[r * 4 + 2] = G[r * 4 + 2];
      A[r * 4 + 3] = G[r * 4 + 3] -
                     (G[r * 4 + 0] * jl[j][0] + G[r * 4 + 1] * jl[j][1] + G[r * 4 + 2] * jl[j][2]);
    }
  }
}

// ---------------- K2: B prep  Bbuf[n][k]: 0..206 posedirs, 207..216 shapedirs, rest 0 ----------------
__global__ void k_prepb(const float* __restrict__ pdirs, const float* __restrict__ sdirs,
                        unsigned short* __restrict__ Bbuf) {
  int idx = blockIdx.x * 256 + threadIdx.x;  // NCOLP*28
  int n = idx / 28, k8 = idx % 28;
  int kbase = k8 * 8;
  ushort8 o;
#pragma unroll
  for (int e = 0; e < 8; ++e) {
    int k = kbase + e;
    float v = 0.f;
    if (n < NCOL) {
      if (k < 207) v = pdirs[(size_t)n * 207 + k];
      else if (k < 217) v = sdirs[(size_t)n * 10 + (k - 207)];
    }
    o[e] = bf16_rne(v);
  }
  *(ushort8*)(Bbuf + (size_t)n * KK + kbase) = o;
}

// ---------------- K3a: MFMA GEMM -> packed bf16 vp2[bpair][col] ----------------
__launch_bounds__(256)
__global__ void k_gemm_b(const unsigned short* __restrict__ Abuf,
                         const unsigned short* __restrict__ Bbuf,
                         const float* __restrict__ vtemp, unsigned* __restrict__ vp2) {
  int tid = threadIdx.x;
  int wid = tid >> 6, lane = tid & 63;
  int lo = lane & 15, hi = lane >> 4;
  int n0 = blockIdx.x * 128 + wid * 32;
  int m0b = blockIdx.y * 64;

  bf16x8 Bf[2][7];
#pragma unroll
  for (int s = 0; s < 2; ++s) {
    const unsigned short* brow = Bbuf + (size_t)(n0 + s * 16 + lo) * KK + hi * 8;
#pragma unroll
    for (int kc = 0; kc < 7; ++kc)
      Bf[s][kc] = *(const bf16x8*)(brow + kc * 32);
  }

  int col0 = n0 + lo;
  int col1 = n0 + 16 + lo;
  float vt0 = (col0 < NCOL) ? vtemp[col0] : 0.f;
  float vt1 = (col1 < NCOL) ? vtemp[col1] : 0.f;

#pragma unroll
  for (int mt = 0; mt < 4; ++mt) {
    int m0 = m0b + mt * 16;
    const unsigned short* arow = Abuf + (size_t)(m0 + lo) * KK + hi * 8;
    f32x4 acc0 = {vt0, vt0, vt0, vt0};
    f32x4 acc1 = {vt1, vt1, vt1, vt1};
#pragma unroll
    for (int kc = 0; kc < 7; ++kc) {
      bf16x8 Af = *(const bf16x8*)(arow + kc * 32);
      acc0 = __builtin_amdgcn_mfma_f32_16x16x32_bf16(Af, Bf[0][kc], acc0, 0, 0, 0);
      acc1 = __builtin_amdgcn_mfma_f32_16x16x32_bf16(Af, Bf[1][kc], acc1, 0, 0, 0);
    }
    int bp0 = m0 / 2 + hi * 2;  // batch-pair row
#pragma unroll
    for (int rp = 0; rp < 2; ++rp) {
      unsigned p0 = (unsigned)bf16_rne(acc0[2 * rp]) | ((unsigned)bf16_rne(acc0[2 * rp + 1]) << 16);
      unsigned p1 = (unsigned)bf16_rne(acc1[2 * rp]) | ((unsigned)bf16_rne(acc1[2 * rp + 1]) << 16);
      vp2[(size_t)(bp0 + rp) * NCOLP + col0] = p0;
      vp2[(size_t)(bp0 + rp) * NCOLP + col1] = p1;
    }
  }
}

// ---------------- K4a: skinning from vp2 (bf16 pairs); 2 batches/thread ----------------
__launch_bounds__(256)
__global__ void k_skin_b(const float* __restrict__ wgt, const float* __restrict__ Amat,
                         const unsigned* __restrict__ vp2, float* __restrict__ out) {
  int tid = threadIdx.x;
  int tv = tid & 63;
  int bg = __builtin_amdgcn_readfirstlane(tid >> 6);  // wave-uniform
  int vg = blockIdx.x * VT + tv;
  int b0 = blockIdx.y * 8;
  bool vok = vg < NV;

  float w[24];
  if (vok) {
    const f4* wp = (const f4*)(wgt + (size_t)vg * 24);
#pragma unroll
    for (int q = 0; q < 6; ++q) {
      f4 t = wp[q];
      w[q * 4 + 0] = t.x; w[q * 4 + 1] = t.y; w[q * 4 + 2] = t.z; w[q * 4 + 3] = t.w;
    }
  } else {
#pragma unroll
    for (int q = 0; q < 24; ++q) w[q] = 0.f;
  }

  // vp for batch pair P = (b0 + bg*2)/2
  int P = b0 / 2 + bg;
  unsigned px = vp2[(size_t)P * NCOLP + 3 * vg + 0];
  unsigned py = vp2[(size_t)P * NCOLP + 3 * vg + 1];
  unsigned pz = vp2[(size_t)P * NCOLP + 3 * vg + 2];
  float vpx[2] = {bf16lo_f(px), bf16hi_f(px)};
  float vpy[2] = {bf16lo_f(py), bf16hi_f(py)};
  float vpz[2] = {bf16lo_f(pz), bf16hi_f(pz)};

  // T[e] = sum_j w[j] * A[b0+bg*2+e][j]  — wave-uniform scalar loads
  const float* Abase = Amat + (size_t)(b0 + bg * 2) * 288;
  float T[2][12];
#pragma unroll
  for (int e = 0; e < 2; ++e)
#pragma unroll
    for (int q = 0; q < 12; ++q) T[e][q] = 0.f;

#pragma unroll
  for (int j = 0; j < NJ; ++j) {
    float wv = w[j];
#pragma unroll
    for (int q = 0; q < 12; ++q) {
      T[0][q] += wv * Abase[j * 12 + q];
      T[1][q] += wv * Abase[288 + j * 12 + q];
    }
  }

  if (vok) {
#pragma unroll
    for (int e = 0; e < 2; ++e) {
      int bl = b0 + bg * 2 + e;
      float* o = out + ((size_t)bl * NV + vg) * 3;
      o[0] = T[e][0] * vpx[e] + T[e][1] * vpy[e] + T[e][2]  * vpz[e] + T[e][3];
      o[1] = T[e][4] * vpx[e] + T[e][5] * vpy[e] + T[e][6]  * vpz[e] + T[e][7];
      o[2] = T[e][8] * vpx[e] + T[e][9] * vpy[e] + T[e][10] * vpz[e] + T[e][11];
    }
  }
}

// ---------------- Fallback path (R4): f32 vp via d_out ----------------
__launch_bounds__(256)
__global__ void k_gemm_f(const unsigned short* __restrict__ Abuf,
                         const unsigned short* __restrict__ Bbuf,
                         const float* __restrict__ vtemp, float* __restrict__ out) {
  int tid = threadIdx.x;
  int wid = tid >> 6, lane = tid & 63;
  int lo = lane & 15, hi = lane >> 4;
  int n0 = blockIdx.x * 128 + wid * 32;
  int m0b = blockIdx.y * 64;

  bf16x8 Bf[2][7];
#pragma unroll
  for (int s = 0; s < 2; ++s) {
    const unsigned short* brow = Bbuf + (size_t)(n0 + s * 16 + lo) * KK + hi * 8;
#pragma unroll
    for (int kc = 0; kc < 7; ++kc)
      Bf[s][kc] = *(const bf16x8*)(brow + kc * 32);
  }
  int col0 = n0 + lo, col1 = n0 + 16 + lo;
  float vt0 = (col0 < NCOL) ? vtemp[col0] : 0.f;
  float vt1 = (col1 < NCOL) ? vtemp[col1] : 0.f;

#pragma unroll
  for (int mt = 0; mt < 4; ++mt) {
    int m0 = m0b + mt * 16;
    const unsigned short* arow = Abuf + (size_t)(m0 + lo) * KK + hi * 8;
    f32x4 acc0 = {vt0, vt0, vt0, vt0};
    f32x4 acc1 = {vt1, vt1, vt1, vt1};
#pragma unroll
    for (int kc = 0; kc < 7; ++kc) {
      bf16x8 Af = *(const bf16x8*)(arow + kc * 32);
      acc0 = __builtin_amdgcn_mfma_f32_16x16x32_bf16(Af, Bf[0][kc], acc0, 0, 0, 0);
      acc1 = __builtin_amdgcn_mfma_f32_16x16x32_bf16(Af, Bf[1][kc], acc1, 0, 0, 0);
    }
    if (col0 < NCOL) {
#pragma unroll
      for (int r = 0; r < 4; ++r)
        out[(size_t)(m0 + hi * 4 + r) * NCOL + col0] = acc0[r];
    }
    if (col1 < NCOL) {
#pragma unroll
      for (int r = 0; r < 4; ++r)
        out[(size_t)(m0 + hi * 4 + r) * NCOL + col1] = acc1[r];
    }
  }
}

__launch_bounds__(256)
__global__ void k_skin_f(const float* __restrict__ wgt, const float* __restrict__ Amat,
                         float* __restrict__ out) {
  int tid = threadIdx.x;
  int vt0 = blockIdx.x * VT, b0 = blockIdx.y * 16;
  int tv = tid & 63;
  int bg = __builtin_amdgcn_readfirstlane(tid >> 6);
  int vg = vt0 + tv;
  bool vok = vg < NV;

  float w[24];
  if (vok) {
    const f4* wp = (const f4*)(wgt + (size_t)vg * 24);
#pragma unroll
    for (int q = 0; q < 6; ++q) {
      f4 t = wp[q];
      w[q * 4 + 0] = t.x; w[q * 4 + 1] = t.y; w[q * 4 + 2] = t.z; w[q * 4 + 3] = t.w;
    }
  } else {
#pragma unroll
    for (int q = 0; q < 24; ++q) w[q] = 0.f;
  }

  float vp[4][3];
#pragma unroll
  for (int k = 0; k < 4; ++k) {
    int bl = b0 + bg * 4 + k;
    const float* ip = out + ((size_t)bl * NV + vg) * 3;
    vp[k][0] = vok ? ip[0] : 0.f;
    vp[k][1] = vok ? ip[1] : 0.f;
    vp[k][2] = vok ? ip[2] : 0.f;
  }

  const float* Abase = Amat + (size_t)(b0 + bg * 4) * 288;
  float T[4][12];
#pragma unroll
  for (int k = 0; k < 4; ++k)
#pragma unroll
    for (int q = 0; q < 12; ++q) T[k][q] = 0.f;

  for (int j = 0; j < NJ; ++j) {
    float wv = w[j];
#pragma unroll
    for (int k = 0; k < 4; ++k) {
      const float* Ak = Abase + k * 288 + j * 12;
#pragma unroll
      for (int q = 0; q < 12; ++q) T[k][q] += wv * Ak[q];
    }
  }

  if (vok) {
#pragma unroll
    for (int k = 0; k < 4; ++k) {
      int bl = b0 + bg * 4 + k;
      float* o = out + ((size_t)bl * NV + vg) * 3;
      o[0] = T[k][0] * vp[k][0] + T[k][1] * vp[k][1] + T[k][2]  * vp[k][2] + T[k][3];
      o[1] = T[k][4] * vp[k][0] + T[k][5] * vp[k][1] + T[k][6]  * vp[k][2] + T[k][7];
      o[2] = T[k][8] * vp[k][0] + T[k][9] * vp[k][1] + T[k][10] * vp[k][2] + T[k][11];
    }
  }
}

extern "C" void kernel_launch(void* const* d_in, const int* in_sizes, int n_in,
                              void* d_out, int out_size, void* d_ws, size_t ws_size,
                              hipStream_t stream) {
  const float* pose   = (const float*)d_in[0];
  const float* beta   = (const float*)d_in[1];
  const float* vtemp  = (const float*)d_in[2];
  const float* sdirs  = (const float*)d_in[3];
  const float* pdirs  = (const float*)d_in[4];
  const float* Jreg   = (const float*)d_in[5];
  const float* wgt    = (const float*)d_in[6];
  const int*   parent = (const int*)d_in[7];
  float* out = (float*)d_out;

  char* wsb = (char*)d_ws;
  unsigned short* Abuf = (unsigned short*)wsb;
  unsigned short* Bbuf = (unsigned short*)(wsb + 229376);
  float*  Amat = (float*)(wsb + 9519104);
  float*  JSp  = (float*)(wsb + 10108928);
  float*  part = (float*)(wsb + 10112096);
  unsigned* vp2 = (unsigned*)(wsb + VP2_OFF);

  hipLaunchKernelGGL(k_jregA, dim3(NJ, 8), dim3(256), 0, stream, Jreg, vtemp, sdirs, part);
  hipLaunchKernelGGL(k_jregB, dim3(4), dim3(256), 0, stream, part, JSp);
  hipLaunchKernelGGL(k_prepb, dim3((NCOLP * 28) / 256), dim3(256), 0, stream, pdirs, sdirs, Bbuf);
  hipLaunchKernelGGL(k_batch, dim3(BATCH), dim3(64), 0, stream, pose, beta, parent, JSp, Abuf, Amat);

  if (ws_size >= WS_NEED) {
    hipLaunchKernelGGL(k_gemm_b, dim3(NCOLP / 128, 8), dim3(256), 0, stream, Abuf, Bbuf, vtemp, vp2);
    hipLaunchKernelGGL(k_skin_b, dim3((NV + VT - 1) / VT, BATCH / 8), dim3(256), 0, stream,
                       wgt, Amat, vp2, out);
  } else {
    hipLaunchKernelGGL(k_gemm_f, dim3(NCOLP / 128, 8), dim3(256), 0, stream, Abuf, Bbuf, vtemp, out);
    hipLaunchKernelGGL(k_skin_f, dim3((NV + VT - 1) / VT, BATCH / 16), dim3(256), 0, stream,
                       wgt, Amat, out);
  }
}

// Round 7
// 83.002 us; speedup vs baseline: 3.2723x; 1.2490x over previous
//
#include <hip/hip_runtime.h>

#define NV 6890
#define NVP16 6912   // padded to 16
#define NJ 24
#define BATCH 512
#define NCOL 20670   // NV*3
#define NCOLP 20736  // padded to 128*162
#define KK 224       // 207 pose + 10 beta + 7 zero
#define VT 64
#define JCH 864      // vert chunk for jreg stage A (8*864 >= 6890)

typedef float f4 __attribute__((ext_vector_type(4)));
typedef float f32x4 __attribute__((ext_vector_type(4)));
typedef short bf16x8 __attribute__((ext_vector_type(8)));
typedef unsigned short ushort8 __attribute__((ext_vector_type(8)));

// ws layout (bytes):
//   Abuf   ushort[512][224]      @ 0         (229376)
//   Bbuf   ushort[20736][224]    @ 229376    (9289728)  end 9519104
//   Amat/Amd (fallback f32 [512][288] | new bf16 [512][16][32]) @ 9519104  end 10108928
//   JSp    float[24][33]         @ 10108928  (3168)
//   part   float[24][8][33]      @ 10112096  (6336)
//   vp2    uint[256][20736]      @ 10137600  (21233664) end 31371264
//   Wb     ushort[6912][32]      @ 31371264  (442368)   end 31813632
#define VP2_OFF 10137600
#define WB_OFF  31371264
#define WS_NEED_OLD 31371264ull
#define WS_NEED_NEW 31813632ull

__device__ __forceinline__ unsigned short bf16_rne(float x) {
  union { float f; unsigned u; } c; c.f = x;
  unsigned r = c.u + 0x7fffu + ((c.u >> 16) & 1u);
  return (unsigned short)(r >> 16);
}
__device__ __forceinline__ float bf16lo_f(unsigned u) {
  union { unsigned u; float f; } c; c.u = u << 16; return c.f;
}
__device__ __forceinline__ float bf16hi_f(unsigned u) {
  union { unsigned u; float f; } c; c.u = u & 0xFFFF0000u; return c.f;
}

// ---------------- K0a: partial JS reduction, grid (24, 8) ----------------
__global__ void k_jregA(const float* __restrict__ Jreg, const float* __restrict__ vtemp,
                        const float* __restrict__ sdirs, float* __restrict__ partial) {
  int j = blockIdx.x, bz = blockIdx.y;
  int tid = threadIdx.x;
  float acc[33];
#pragma unroll
  for (int i = 0; i < 33; ++i) acc[i] = 0.f;
  int v0 = bz * JCH;
  int v1 = v0 + JCH; if (v1 > NV) v1 = NV;
  for (int v = v0 + tid; v < v1; v += 256) {
    float w = Jreg[(size_t)j * NV + v];
    const float* vt = vtemp + (size_t)v * 3;
    acc[0] += w * vt[0]; acc[1] += w * vt[1]; acc[2] += w * vt[2];
    const float* sdv = sdirs + (size_t)v * 30;
#pragma unroll
    for (int t = 0; t < 30; ++t) acc[3 + t] += w * sdv[t];
  }
#pragma unroll
  for (int i = 0; i < 33; ++i) {
    float a = acc[i];
#pragma unroll
    for (int s = 32; s > 0; s >>= 1) a += __shfl_xor(a, s, 64);
    acc[i] = a;
  }
  __shared__ float red[4][34];
  int lane = tid & 63, wv = tid >> 6;
  if (lane == 0) {
#pragma unroll
    for (int i = 0; i < 33; ++i) red[wv][i] = acc[i];
  }
  __syncthreads();
  if (tid < 33) {
    float s = red[0][tid] + red[1][tid] + red[2][tid] + red[3][tid];
    partial[((size_t)j * 8 + bz) * 33 + tid] = s;
  }
}

// ---------------- K0b: sum the 8 partials ----------------
__global__ void k_jregB(const float* __restrict__ partial, float* __restrict__ JSp) {
  int i = blockIdx.x * 256 + threadIdx.x;
  if (i < NJ * 33) {
    int j = i / 33, q = i % 33;
    float s = 0.f;
#pragma unroll
    for (int bz = 0; bz < 8; ++bz) s += partial[((size_t)j * 8 + bz) * 33 + q];
    JSp[i] = s;
  }
}

// ---------------- K1: per-batch joints, rodrigues, chain, A matrices, Abuf ----------------
// mode=1: write bf16 Amd[b][16][32]; mode=0: write f32 Amat[b][24][12]
__global__ void k_batch(const float* __restrict__ pose, const float* __restrict__ beta,
                        const int* __restrict__ parent, const float* __restrict__ JSp,
                        unsigned short* __restrict__ Abuf, float* __restrict__ Amat,
                        unsigned short* __restrict__ Amd, int mode) {
  int b = blockIdx.x;
  int j = threadIdx.x;  // 64 threads
  __shared__ float jl[NJ][3];
  __shared__ float gl[NJ][16];

  // zero-fill Amd tile (16x32 ushorts = 512; 8 per thread), ordered by the syncs below
  if (mode) {
    ushort8 z = {0, 0, 0, 0, 0, 0, 0, 0};
    *(ushort8*)(Amd + (size_t)b * 512 + j * 8) = z;
  }

  float bt[10];
#pragma unroll
  for (int t = 0; t < 10; ++t) bt[t] = beta[b * 10 + t];

  float R[9];
  float Jj[3] = {0.f, 0.f, 0.f};
  if (j < NJ) {
    const float* js = JSp + j * 33;
#pragma unroll
    for (int c = 0; c < 3; ++c) {
      float a = js[c];
#pragma unroll
      for (int t = 0; t < 10; ++t) a += js[3 + c * 10 + t] * bt[t];
      Jj[c] = a;
      jl[j][c] = a;
    }
    float rx = pose[b * 72 + j * 3 + 0];
    float ry = pose[b * 72 + j * 3 + 1];
    float rz = pose[b * 72 + j * 3 + 2];
    float theta = sqrtf(rx * rx + ry * ry + rz * rz) + 1e-8f;
    float inv = 1.f / theta;
    float ax = rx * inv, ay = ry * inv, az = rz * inv;
    float c = cosf(theta), s = sinf(theta), oc = 1.f - c;
    R[0] = c + oc * ax * ax;      R[1] = oc * ax * ay - s * az; R[2] = oc * ax * az + s * ay;
    R[3] = oc * ax * ay + s * az; R[4] = c + oc * ay * ay;      R[5] = oc * ay * az - s * ax;
    R[6] = oc * ax * az - s * ay; R[7] = oc * ay * az + s * ax; R[8] = c + oc * az * az;
  }
  __syncthreads();

  // Abuf cols: 0..206 lrotmin, 207..216 beta, 217..223 zero (bf16)
  if (j >= 1 && j < NJ) {
    unsigned short* lr = Abuf + b * KK + (j - 1) * 9;
#pragma unroll
    for (int k = 0; k < 9; ++k)
      lr[k] = bf16_rne(R[k] - ((k == 0 || k == 4 || k == 8) ? 1.f : 0.f));
  }
  if (j >= 32 && j < 42) Abuf[b * KK + 207 + (j - 32)] = bf16_rne(bt[j - 32]);
  if (j >= 42 && j < 49) Abuf[b * KK + 207 + (j - 32)] = 0;

  if (j < NJ) {
    int par = (j == 0) ? 0 : parent[j - 1];
#pragma unroll
    for (int r = 0; r < 3; ++r) {
      gl[j][r * 4 + 0] = R[r * 3 + 0];
      gl[j][r * 4 + 1] = R[r * 3 + 1];
      gl[j][r * 4 + 2] = R[r * 3 + 2];
      gl[j][r * 4 + 3] = (j == 0) ? Jj[r] : Jj[r] - jl[par][r];
    }
  }
  __syncthreads();

  if (j < NJ) {
    int a[12];
    int n = 0, cur = j;
    while (cur != 0 && n < 12) { a[n++] = cur; cur = parent[cur - 1]; }
    float G[12];
#pragma unroll
    for (int r = 0; r < 3; ++r)
#pragma unroll
      for (int cc = 0; cc < 4; ++cc) G[r * 4 + cc] = gl[0][r * 4 + cc];
    for (int i = n - 1; i >= 0; --i) {
      const float* L = gl[a[i]];
      float C[12];
#pragma unroll
      for (int r = 0; r < 3; ++r) {
#pragma unroll
        for (int cc = 0; cc < 4; ++cc) {
          float sacc = (cc == 3) ? G[r * 4 + 3] : 0.f;
#pragma unroll
          for (int k = 0; k < 3; ++k) sacc += G[r * 4 + k] * L[k * 4 + cc];
          C[r * 4 + cc] = sacc;
        }
      }
#pragma unroll
      for (int k = 0; k < 12; ++k) G[k] = C[k];
    }
    // rest subtraction on last column
    float Aval[12];
#pragma unroll
    for (int r = 0; r < 3; ++r) {
      Aval[r * 4 + 0] = G[r * 4 + 0];
      Aval[r * 4 + 1] = G[r * 4 + 1];
      Aval[r * 4 + 2] = G[r * 4 + 2];
      Aval[r * 4 + 3] = G[r * 4 + 3] -
                        (G[r * 4 + 0] * jl[j][0] + G[r * 4 + 1] * jl[j][1] + G[r * 4 + 2] * jl[j][2]);
    }
    if (mode) {
      // Amd[b][row=x*4+y][j] = A[b][j][x][y]  (bf16)
#pragma unroll
      for (int r = 0; r < 3; ++r)
#pragma unroll
        for (int cc = 0; cc < 4; ++cc)
          Amd[(size_t)b * 512 + (r * 4 + cc) * 32 + j] = bf16_rne(Aval[r * 4 + cc]);
    } else {
      float* A = Amat + b * 288 + j * 12;
#pragma unroll
      for (int q = 0; q < 12; ++q) A[q] = Aval[q];
    }
  }
}

// ---------------- K2: B prep  Bbuf[n][k]: 0..206 posedirs, 207..216 shapedirs, rest 0 ----------------
__global__ void k_prepb(const float* __restrict__ pdirs, const float* __restrict__ sdirs,
                        unsigned short* __restrict__ Bbuf) {
  int idx = blockIdx.x * 256 + threadIdx.x;  // NCOLP*28
  int n = idx / 28, k8 = idx % 28;
  int kbase = k8 * 8;
  ushort8 o;
#pragma unroll
  for (int e = 0; e < 8; ++e) {
    int k = kbase + e;
    float v = 0.f;
    if (n < NCOL) {
      if (k < 207) v = pdirs[(size_t)n * 207 + k];
      else if (k < 217) v = sdirs[(size_t)n * 10 + (k - 207)];
    }
    o[e] = bf16_rne(v);
  }
  *(ushort8*)(Bbuf + (size_t)n * KK + kbase) = o;
}

// ---------------- K2b: W prep  Wb[v][32]: 0..23 weights, 24..31 zero ----------------
__global__ void k_prepw(const float* __restrict__ wgt, unsigned short* __restrict__ Wb) {
  int idx = blockIdx.x * 256 + threadIdx.x;  // NVP16*4 = 27648
  int v = idx >> 2, q = idx & 3;
  ushort8 o = {0, 0, 0, 0, 0, 0, 0, 0};
  if (v < NV && q < 3) {
#pragma unroll
    for (int e = 0; e < 8; ++e) o[e] = bf16_rne(wgt[(size_t)v * 24 + q * 8 + e]);
  }
  *(ushort8*)(Wb + (size_t)v * 32 + q * 8) = o;
}

// ---------------- K3: MFMA GEMM -> packed bf16 vp2[bpair][col] ----------------
__launch_bounds__(256)
__global__ void k_gemm_b(const unsigned short* __restrict__ Abuf,
                         const unsigned short* __restrict__ Bbuf,
                         const float* __restrict__ vtemp, unsigned* __restrict__ vp2) {
  int tid = threadIdx.x;
  int wid = tid >> 6, lane = tid & 63;
  int lo = lane & 15, hi = lane >> 4;
  int n0 = blockIdx.x * 128 + wid * 32;
  int m0b = blockIdx.y * 64;

  bf16x8 Bf[2][7];
#pragma unroll
  for (int s = 0; s < 2; ++s) {
    const unsigned short* brow = Bbuf + (size_t)(n0 + s * 16 + lo) * KK + hi * 8;
#pragma unroll
    for (int kc = 0; kc < 7; ++kc)
      Bf[s][kc] = *(const bf16x8*)(brow + kc * 32);
  }

  int col0 = n0 + lo;
  int col1 = n0 + 16 + lo;
  float vt0 = (col0 < NCOL) ? vtemp[col0] : 0.f;
  float vt1 = (col1 < NCOL) ? vtemp[col1] : 0.f;

#pragma unroll
  for (int mt = 0; mt < 4; ++mt) {
    int m0 = m0b + mt * 16;
    const unsigned short* arow = Abuf + (size_t)(m0 + lo) * KK + hi * 8;
    f32x4 acc0 = {vt0, vt0, vt0, vt0};
    f32x4 acc1 = {vt1, vt1, vt1, vt1};
#pragma unroll
    for (int kc = 0; kc < 7; ++kc) {
      bf16x8 Af = *(const bf16x8*)(arow + kc * 32);
      acc0 = __builtin_amdgcn_mfma_f32_16x16x32_bf16(Af, Bf[0][kc], acc0, 0, 0, 0);
      acc1 = __builtin_amdgcn_mfma_f32_16x16x32_bf16(Af, Bf[1][kc], acc1, 0, 0, 0);
    }
    int bp0 = m0 / 2 + hi * 2;  // batch-pair row (lo16 = even batch, hi16 = odd)
#pragma unroll
    for (int rp = 0; rp < 2; ++rp) {
      unsigned p0 = (unsigned)bf16_rne(acc0[2 * rp]) | ((unsigned)bf16_rne(acc0[2 * rp + 1]) << 16);
      unsigned p1 = (unsigned)bf16_rne(acc1[2 * rp]) | ((unsigned)bf16_rne(acc1[2 * rp + 1]) << 16);
      if (col0 < NCOL) vp2[(size_t)(bp0 + rp) * NCOLP + col0] = p0;
      if (col1 < NCOL) vp2[(size_t)(bp0 + rp) * NCOLP + col1] = p1;
    }
  }
}

// ---------------- K4: MFMA skinning  T = W·Amd per batch, apply vp, write out ----------------
// grid (NVP16/64, 8), 256 threads. Each wave: 16 verts, 64 batches (32 pairs).
// C-frag: lane(lo,hi) holds T[x=hi][y=0..3] of vert n0+lo -> out = 3 FMA + add.
__launch_bounds__(256)
__global__ void k_skin_m(const unsigned short* __restrict__ Amd,
                         const unsigned short* __restrict__ Wb,
                         const unsigned* __restrict__ vp2, float* __restrict__ out) {
  int tid = threadIdx.x;
  int wid = tid >> 6, lane = tid & 63;
  int lo = lane & 15, hi = lane >> 4;
  int n0 = blockIdx.x * 64 + wid * 16;
  int vg = n0 + lo;
  bool sok = (vg < NV) && (hi < 3);

  // W fragment: loaded once, reused for all batches
  bf16x8 Wf = *(const bf16x8*)(Wb + (size_t)vg * 32 + hi * 8);

  const unsigned* vpp = vp2 + 3 * (size_t)vg;
  int p0 = blockIdx.y * 32;
#pragma unroll 2
  for (int p = p0; p < p0 + 32; ++p) {
    int b0 = 2 * p;
    bf16x8 Af0 = *(const bf16x8*)(Amd + (size_t)b0 * 512 + lo * 32 + hi * 8);
    bf16x8 Af1 = *(const bf16x8*)(Amd + ((size_t)b0 + 1) * 512 + lo * 32 + hi * 8);
    unsigned ux = vpp[(size_t)p * NCOLP + 0];
    unsigned uy = vpp[(size_t)p * NCOLP + 1];
    unsigned uz = vpp[(size_t)p * NCOLP + 2];
    f32x4 z = {0.f, 0.f, 0.f, 0.f};
    f32x4 c0 = __builtin_amdgcn_mfma_f32_16x16x32_bf16(Af0, Wf, z, 0, 0, 0);
    f32x4 c1 = __builtin_amdgcn_mfma_f32_16x16x32_bf16(Af1, Wf, z, 0, 0, 0);
    float o0 = c0[0] * bf16lo_f(ux) + c0[1] * bf16lo_f(uy) + c0[2] * bf16lo_f(uz) + c0[3];
    float o1 = c1[0] * bf16hi_f(ux) + c1[1] * bf16hi_f(uy) + c1[2] * bf16hi_f(uz) + c1[3];
    if (sok) {
      out[((size_t)b0 * NV + vg) * 3 + hi] = o0;
      out[(((size_t)b0 + 1) * NV + vg) * 3 + hi] = o1;
    }
  }
}

// ---------------- Fallback skinning (R6): per-thread T, scalar A loads ----------------
__launch_bounds__(256)
__global__ void k_skin_b(const float* __restrict__ wgt, const float* __restrict__ Amat,
                         const unsigned* __restrict__ vp2, float* __restrict__ out) {
  int tid = threadIdx.x;
  int tv = tid & 63;
  int bg = __builtin_amdgcn_readfirstlane(tid >> 6);
  int vg = blockIdx.x * VT + tv;
  int b0 = blockIdx.y * 8;
  bool vok = vg < NV;

  float w[24];
  if (vok) {
    const f4* wp = (const f4*)(wgt + (size_t)vg * 24);
#pragma unroll
    for (int q = 0; q < 6; ++q) {
      f4 t = wp[q];
      w[q * 4 + 0] = t.x; w[q * 4 + 1] = t.y; w[q * 4 + 2] = t.z; w[q * 4 + 3] = t.w;
    }
  } else {
#pragma unroll
    for (int q = 0; q < 24; ++q) w[q] = 0.f;
  }

  int P = b0 / 2 + bg;
  unsigned px = vp2[(size_t)P * NCOLP + 3 * vg + 0];
  unsigned py = vp2[(size_t)P * NCOLP + 3 * vg + 1];
  unsigned pz = vp2[(size_t)P * NCOLP + 3 * vg + 2];
  float vpx[2] = {bf16lo_f(px), bf16hi_f(px)};
  float vpy[2] = {bf16lo_f(py), bf16hi_f(py)};
  float vpz[2] = {bf16lo_f(pz), bf16hi_f(pz)};

  const float* Abase = Amat + (size_t)(b0 + bg * 2) * 288;
  float T[2][12];
#pragma unroll
  for (int e = 0; e < 2; ++e)
#pragma unroll
    for (int q = 0; q < 12; ++q) T[e][q] = 0.f;

#pragma unroll
  for (int j = 0; j < NJ; ++j) {
    float wv = w[j];
#pragma unroll
    for (int q = 0; q < 12; ++q) {
      T[0][q] += wv * Abase[j * 12 + q];
      T[1][q] += wv * Abase[288 + j * 12 + q];
    }
  }

  if (vok) {
#pragma unroll
    for (int e = 0; e < 2; ++e) {
      int bl = b0 + bg * 2 + e;
      float* o = out + ((size_t)bl * NV + vg) * 3;
      o[0] = T[e][0] * vpx[e] + T[e][1] * vpy[e] + T[e][2]  * vpz[e] + T[e][3];
      o[1] = T[e][4] * vpx[e] + T[e][5] * vpy[e] + T[e][6]  * vpz[e] + T[e][7];
      o[2] = T[e][8] * vpx[e] + T[e][9] * vpy[e] + T[e][10] * vpz[e] + T[e][11];
    }
  }
}

extern "C" void kernel_launch(void* const* d_in, const int* in_sizes, int n_in,
                              void* d_out, int out_size, void* d_ws, size_t ws_size,
                              hipStream_t stream) {
  const float* pose   = (const float*)d_in[0];
  const float* beta   = (const float*)d_in[1];
  const float* vtemp  = (const float*)d_in[2];
  const float* sdirs  = (const float*)d_in[3];
  const float* pdirs  = (const float*)d_in[4];
  const float* Jreg   = (const float*)d_in[5];
  const float* wgt    = (const float*)d_in[6];
  const int*   parent = (const int*)d_in[7];
  float* out = (float*)d_out;

  char* wsb = (char*)d_ws;
  unsigned short* Abuf = (unsigned short*)wsb;
  unsigned short* Bbuf = (unsigned short*)(wsb + 229376);
  float*  Amat = (float*)(wsb + 9519104);
  unsigned short* Amd = (unsigned short*)(wsb + 9519104);  // overlays Amat
  float*  JSp  = (float*)(wsb + 10108928);
  float*  part = (float*)(wsb + 10112096);
  unsigned* vp2 = (unsigned*)(wsb + VP2_OFF);
  unsigned short* Wb = (unsigned short*)(wsb + WB_OFF);

  int newpath = (ws_size >= WS_NEED_NEW) ? 1 : 0;

  hipLaunchKernelGGL(k_jregA, dim3(NJ, 8), dim3(256), 0, stream, Jreg, vtemp, sdirs, part);
  hipLaunchKernelGGL(k_jregB, dim3(4), dim3(256), 0, stream, part, JSp);
  hipLaunchKernelGGL(k_prepb, dim3((NCOLP * 28) / 256), dim3(256), 0, stream, pdirs, sdirs, Bbuf);
  if (newpath)
    hipLaunchKernelGGL(k_prepw, dim3((NVP16 * 4) / 256), dim3(256), 0, stream, wgt, Wb);
  hipLaunchKernelGGL(k_batch, dim3(BATCH), dim3(64), 0, stream, pose, beta, parent, JSp,
                     Abuf, Amat, Amd, newpath);
  hipLaunchKernelGGL(k_gemm_b, dim3(NCOLP / 128, 8), dim3(256), 0, stream, Abuf, Bbuf, vtemp, vp2);
  if (newpath) {
    hipLaunchKernelGGL(k_skin_m, dim3(NVP16 / 64, 8), dim3(256), 0, stream, Amd, Wb, vp2, out);
  } else {
    hipLaunchKernelGGL(k_skin_b, dim3((NV + VT - 1) / VT, BATCH / 8), dim3(256), 0, stream,
                       wgt, Amat, vp2, out);
  }
}

// Round 8
// 81.752 us; speedup vs baseline: 3.3223x; 1.0153x over previous
//
#include <hip/hip_runtime.h>

#define NV 6890
#define NVP16 6912   // padded to 16
#define NJ 24
#define BATCH 512
#define NCOL 20670   // NV*3
#define NCOLP 20736  // 108*192
#define KK 224       // 207 pose + 10 beta + 7 zero
#define JCH 864      // vert chunk for jreg stage A (8*864 >= 6890)
#define LSTR 197     // LDS pair-row stride (uints)

typedef float f4 __attribute__((ext_vector_type(4)));
typedef float f32x4 __attribute__((ext_vector_type(4)));
typedef short bf16x8 __attribute__((ext_vector_type(8)));
typedef unsigned short ushort8 __attribute__((ext_vector_type(8)));

// ws layout (bytes):
//   Abuf  ushort[512][224]    @ 0         (229376)
//   Bbuf  ushort[20736][224]  @ 229376    (9289728)  end 9519104
//   Amd   ushort[512][16][32] @ 9519104   (524288)   end 10043392
//   part  float[24][8][33]    @ 10043392  (25344)    end 10068736
//   Wb    ushort[6912][32]    @ 10068736  (442368)   end 10511104

__device__ __forceinline__ unsigned short bf16_rne(float x) {
  union { float f; unsigned u; } c; c.f = x;
  unsigned r = c.u + 0x7fffu + ((c.u >> 16) & 1u);
  return (unsigned short)(r >> 16);
}
__device__ __forceinline__ float bf16lo_f(unsigned u) {
  union { unsigned u; float f; } c; c.u = u << 16; return c.f;
}
__device__ __forceinline__ float bf16hi_f(unsigned u) {
  union { unsigned u; float f; } c; c.u = u & 0xFFFF0000u; return c.f;
}

// ---------------- K0: partial JS reduction, grid (24, 8) ----------------
__global__ void k_jregA(const float* __restrict__ Jreg, const float* __restrict__ vtemp,
                        const float* __restrict__ sdirs, float* __restrict__ partial) {
  int j = blockIdx.x, bz = blockIdx.y;
  int tid = threadIdx.x;
  float acc[33];
#pragma unroll
  for (int i = 0; i < 33; ++i) acc[i] = 0.f;
  int v0 = bz * JCH;
  int v1 = v0 + JCH; if (v1 > NV) v1 = NV;
  for (int v = v0 + tid; v < v1; v += 256) {
    float w = Jreg[(size_t)j * NV + v];
    const float* vt = vtemp + (size_t)v * 3;
    acc[0] += w * vt[0]; acc[1] += w * vt[1]; acc[2] += w * vt[2];
    const float* sdv = sdirs + (size_t)v * 30;
#pragma unroll
    for (int t = 0; t < 30; ++t) acc[3 + t] += w * sdv[t];
  }
#pragma unroll
  for (int i = 0; i < 33; ++i) {
    float a = acc[i];
#pragma unroll
    for (int s = 32; s > 0; s >>= 1) a += __shfl_xor(a, s, 64);
    acc[i] = a;
  }
  __shared__ float red[4][34];
  int lane = tid & 63, wv = tid >> 6;
  if (lane == 0) {
#pragma unroll
    for (int i = 0; i < 33; ++i) red[wv][i] = acc[i];
  }
  __syncthreads();
  if (tid < 33) {
    float s = red[0][tid] + red[1][tid] + red[2][tid] + red[3][tid];
    partial[((size_t)j * 8 + bz) * 33 + tid] = s;
  }
}

// ---------------- K1: fused B/W prep ----------------
// idx < NCOLP*28: Bbuf[n][k] = {posedirs | shapedirs | 0} bf16
// else:           Wb[v][32]  = {weights[24], 0...} bf16
__global__ void k_prep(const float* __restrict__ pdirs, const float* __restrict__ sdirs,
                       const float* __restrict__ wgt,
                       unsigned short* __restrict__ Bbuf, unsigned short* __restrict__ Wb) {
  int idx = blockIdx.x * 256 + threadIdx.x;  // NCOLP*28 + NVP16*4 = 608256 = 2376*256
  if (idx < NCOLP * 28) {
    int n = idx / 28, k8 = idx % 28;
    int kbase = k8 * 8;
    ushort8 o;
#pragma unroll
    for (int e = 0; e < 8; ++e) {
      int k = kbase + e;
      float v = 0.f;
      if (n < NCOL) {
        if (k < 207) v = pdirs[(size_t)n * 207 + k];
        else if (k < 217) v = sdirs[(size_t)n * 10 + (k - 207)];
      }
      o[e] = bf16_rne(v);
    }
    *(ushort8*)(Bbuf + (size_t)n * KK + kbase) = o;
  } else {
    int widx = idx - NCOLP * 28;
    int v = widx >> 2, q = widx & 3;
    ushort8 o = {0, 0, 0, 0, 0, 0, 0, 0};
    if (v < NV && q < 3) {
#pragma unroll
      for (int e = 0; e < 8; ++e) o[e] = bf16_rne(wgt[(size_t)v * 24 + q * 8 + e]);
    }
    *(ushort8*)(Wb + (size_t)v * 32 + q * 8) = o;
  }
}

// ---------------- K2: per-batch joints (sums partials inline), rodrigues, chain, Abuf+Amd ----------------
__global__ void k_batch(const float* __restrict__ pose, const float* __restrict__ beta,
                        const int* __restrict__ parent, const float* __restrict__ partial,
                        unsigned short* __restrict__ Abuf, unsigned short* __restrict__ Amd) {
  int b = blockIdx.x;
  int j = threadIdx.x;  // 64 threads
  __shared__ float jl[NJ][3];
  __shared__ float gl[NJ][16];

  // zero-fill Amd tile (16x32 ushorts = 512; 8 per thread)
  {
    ushort8 z = {0, 0, 0, 0, 0, 0, 0, 0};
    *(ushort8*)(Amd + (size_t)b * 512 + j * 8) = z;
  }

  float bt[10];
#pragma unroll
  for (int t = 0; t < 10; ++t) bt[t] = beta[b * 10 + t];

  float R[9];
  float Jj[3] = {0.f, 0.f, 0.f};
  if (j < NJ) {
    // JS[j] = sum of 8 partials (broadcast L2 reads)
    float js[33];
#pragma unroll
    for (int q = 0; q < 33; ++q) js[q] = 0.f;
#pragma unroll
    for (int bz = 0; bz < 8; ++bz) {
      const float* pp = partial + ((size_t)j * 8 + bz) * 33;
#pragma unroll
      for (int q = 0; q < 33; ++q) js[q] += pp[q];
    }
#pragma unroll
    for (int c = 0; c < 3; ++c) {
      float a = js[c];
#pragma unroll
      for (int t = 0; t < 10; ++t) a += js[3 + c * 10 + t] * bt[t];
      Jj[c] = a;
      jl[j][c] = a;
    }
    float rx = pose[b * 72 + j * 3 + 0];
    float ry = pose[b * 72 + j * 3 + 1];
    float rz = pose[b * 72 + j * 3 + 2];
    float theta = sqrtf(rx * rx + ry * ry + rz * rz) + 1e-8f;
    float inv = 1.f / theta;
    float ax = rx * inv, ay = ry * inv, az = rz * inv;
    float c = cosf(theta), s = sinf(theta), oc = 1.f - c;
    R[0] = c + oc * ax * ax;      R[1] = oc * ax * ay - s * az; R[2] = oc * ax * az + s * ay;
    R[3] = oc * ax * ay + s * az; R[4] = c + oc * ay * ay;      R[5] = oc * ay * az - s * ax;
    R[6] = oc * ax * az - s * ay; R[7] = oc * ay * az + s * ax; R[8] = c + oc * az * az;
  }
  __syncthreads();

  // Abuf cols: 0..206 lrotmin, 207..216 beta, 217..223 zero (bf16)
  if (j >= 1 && j < NJ) {
    unsigned short* lr = Abuf + b * KK + (j - 1) * 9;
#pragma unroll
    for (int k = 0; k < 9; ++k)
      lr[k] = bf16_rne(R[k] - ((k == 0 || k == 4 || k == 8) ? 1.f : 0.f));
  }
  if (j >= 32 && j < 42) Abuf[b * KK + 207 + (j - 32)] = bf16_rne(bt[j - 32]);
  if (j >= 42 && j < 49) Abuf[b * KK + 207 + (j - 32)] = 0;

  if (j < NJ) {
    int par = (j == 0) ? 0 : parent[j - 1];
#pragma unroll
    for (int r = 0; r < 3; ++r) {
      gl[j][r * 4 + 0] = R[r * 3 + 0];
      gl[j][r * 4 + 1] = R[r * 3 + 1];
      gl[j][r * 4 + 2] = R[r * 3 + 2];
      gl[j][r * 4 + 3] = (j == 0) ? Jj[r] : Jj[r] - jl[par][r];
    }
  }
  __syncthreads();

  if (j < NJ) {
    int a[12];
    int n = 0, cur = j;
    while (cur != 0 && n < 12) { a[n++] = cur; cur = parent[cur - 1]; }
    float G[12];
#pragma unroll
    for (int r = 0; r < 3; ++r)
#pragma unroll
      for (int cc = 0; cc < 4; ++cc) G[r * 4 + cc] = gl[0][r * 4 + cc];
    for (int i = n - 1; i >= 0; --i) {
      const float* L = gl[a[i]];
      float C[12];
#pragma unroll
      for (int r = 0; r < 3; ++r) {
#pragma unroll
        for (int cc = 0; cc < 4; ++cc) {
          float sacc = (cc == 3) ? G[r * 4 + 3] : 0.f;
#pragma unroll
          for (int k = 0; k < 3; ++k) sacc += G[r * 4 + k] * L[k * 4 + cc];
          C[r * 4 + cc] = sacc;
        }
      }
#pragma unroll
      for (int k = 0; k < 12; ++k) G[k] = C[k];
    }
    float Aval[12];
#pragma unroll
    for (int r = 0; r < 3; ++r) {
      Aval[r * 4 + 0] = G[r * 4 + 0];
      Aval[r * 4 + 1] = G[r * 4 + 1];
      Aval[r * 4 + 2] = G[r * 4 + 2];
      Aval[r * 4 + 3] = G[r * 4 + 3] -
                        (G[r * 4 + 0] * jl[j][0] + G[r * 4 + 1] * jl[j][1] + G[r * 4 + 2] * jl[j][2]);
    }
    // Amd[b][row=x*4+y][j] (bf16), rows 12..15 remain zero
#pragma unroll
    for (int r = 0; r < 3; ++r)
#pragma unroll
      for (int cc = 0; cc < 4; ++cc)
        Amd[(size_t)b * 512 + (r * 4 + cc) * 32 + j] = bf16_rne(Aval[r * 4 + cc]);
  }
}

// ---------------- K3: fused pose-blend GEMM + MFMA skinning ----------------
// grid (108, 8), 256 threads. Tile: 192 cols (=64 verts) x 64 batches.
// Phase 1: vp(bf16-pair packed) -> LDS [32 pairs][LSTR].
// Phase 2: per wave 16 verts x 64 batches: T = Amd x W via MFMA, apply vp, store out.
__launch_bounds__(256)
__global__ void k_gemmskin(const unsigned short* __restrict__ Abuf,
                           const unsigned short* __restrict__ Bbuf,
                           const float* __restrict__ vtemp,
                           const unsigned short* __restrict__ Amd,
                           const unsigned short* __restrict__ Wb,
                           float* __restrict__ out) {
  __shared__ unsigned vp[32 * LSTR];  // 25216 B

  int tid = threadIdx.x;
  int wid = tid >> 6, lane = tid & 63;
  int lo = lane & 15, hi = lane >> 4;
  int n0 = blockIdx.x * 192;
  int bb0 = blockIdx.y * 64;

  // ---- Phase 1: GEMM, 3 strips of 16 cols per wave ----
#pragma unroll
  for (int s = 0; s < 3; ++s) {
    int cb = wid * 48 + s * 16;
    const unsigned short* brow = Bbuf + (size_t)(n0 + cb + lo) * KK + hi * 8;
    bf16x8 Bf[7];
#pragma unroll
    for (int kc = 0; kc < 7; ++kc) Bf[kc] = *(const bf16x8*)(brow + kc * 32);
    int gc = n0 + cb + lo;
    float vt = (gc < NCOL) ? vtemp[gc] : 0.f;
#pragma unroll
    for (int mt = 0; mt < 4; ++mt) {
      const unsigned short* arow = Abuf + (size_t)(bb0 + mt * 16 + lo) * KK + hi * 8;
      f32x4 acc = {vt, vt, vt, vt};
#pragma unroll
      for (int kc = 0; kc < 7; ++kc) {
        bf16x8 Af = *(const bf16x8*)(arow + kc * 32);
        acc = __builtin_amdgcn_mfma_f32_16x16x32_bf16(Af, Bf[kc], acc, 0, 0, 0);
      }
      // rows = batches bb0 + mt*16 + hi*4 + r; pack pairs (even,odd)
#pragma unroll
      for (int rp = 0; rp < 2; ++rp) {
        unsigned pr = (unsigned)bf16_rne(acc[2 * rp]) |
                      ((unsigned)bf16_rne(acc[2 * rp + 1]) << 16);
        vp[(mt * 8 + hi * 2 + rp) * LSTR + cb + lo] = pr;
      }
    }
  }
  __syncthreads();

  // ---- Phase 2: MFMA skinning ----
  int vloc = wid * 16 + lo;
  int vg = blockIdx.x * 64 + vloc;
  bool sok = (vg < NV) && (hi < 3);

  bf16x8 Wf = *(const bf16x8*)(Wb + (size_t)vg * 32 + hi * 8);

#pragma unroll 2
  for (int p = 0; p < 32; ++p) {
    int b0 = bb0 + 2 * p;
    bf16x8 Af0 = *(const bf16x8*)(Amd + (size_t)b0 * 512 + lo * 32 + hi * 8);
    bf16x8 Af1 = *(const bf16x8*)(Amd + ((size_t)b0 + 1) * 512 + lo * 32 + hi * 8);
    unsigned ux = vp[p * LSTR + 3 * vloc + 0];
    unsigned uy = vp[p * LSTR + 3 * vloc + 1];
    unsigned uz = vp[p * LSTR + 3 * vloc + 2];
    f32x4 z = {0.f, 0.f, 0.f, 0.f};
    f32x4 c0 = __builtin_amdgcn_mfma_f32_16x16x32_bf16(Af0, Wf, z, 0, 0, 0);
    f32x4 c1 = __builtin_amdgcn_mfma_f32_16x16x32_bf16(Af1, Wf, z, 0, 0, 0);
    float o0 = c0[0] * bf16lo_f(ux) + c0[1] * bf16lo_f(uy) + c0[2] * bf16lo_f(uz) + c0[3];
    float o1 = c1[0] * bf16hi_f(ux) + c1[1] * bf16hi_f(uy) + c1[2] * bf16hi_f(uz) + c1[3];
    if (sok) {
      out[((size_t)b0 * NV + vg) * 3 + hi] = o0;
      out[(((size_t)b0 + 1) * NV + vg) * 3 + hi] = o1;
    }
  }
}

extern "C" void kernel_launch(void* const* d_in, const int* in_sizes, int n_in,
                              void* d_out, int out_size, void* d_ws, size_t ws_size,
                              hipStream_t stream) {
  const float* pose   = (const float*)d_in[0];
  const float* beta   = (const float*)d_in[1];
  const float* vtemp  = (const float*)d_in[2];
  const float* sdirs  = (const float*)d_in[3];
  const float* pdirs  = (const float*)d_in[4];
  const float* Jreg   = (const float*)d_in[5];
  const float* wgt    = (const float*)d_in[6];
  const int*   parent = (const int*)d_in[7];
  float* out = (float*)d_out;

  char* wsb = (char*)d_ws;
  unsigned short* Abuf = (unsigned short*)wsb;
  unsigned short* Bbuf = (unsigned short*)(wsb + 229376);
  unsigned short* Amd  = (unsigned short*)(wsb + 9519104);
  float* part          = (float*)(wsb + 10043392);
  unsigned short* Wb   = (unsigned short*)(wsb + 10068736);

  hipLaunchKernelGGL(k_jregA, dim3(NJ, 8), dim3(256), 0, stream, Jreg, vtemp, sdirs, part);
  hipLaunchKernelGGL(k_prep, dim3((NCOLP * 28 + NVP16 * 4) / 256), dim3(256), 0, stream,
                     pdirs, sdirs, wgt, Bbuf, Wb);
  hipLaunchKernelGGL(k_batch, dim3(BATCH), dim3(64), 0, stream, pose, beta, parent, part,
                     Abuf, Amd);
  hipLaunchKernelGGL(k_gemmskin, dim3(NCOLP / 192, BATCH / 64), dim3(256), 0, stream,
                     Abuf, Bbuf, vtemp, Amd, Wb, out);
}

// Round 9
// 75.870 us; speedup vs baseline: 3.5799x; 1.0775x over previous
//
#include <hip/hip_runtime.h>

#define NV 6890
#define NVP16 6912   // padded to 16
#define NJ 24
#define BATCH 512
#define NCOL 20670   // NV*3
#define NCOLP 20736  // 108*192
#define KK 224       // 207 pose + 10 beta + 7 zero
#define JCH 864      // vert chunk for jreg stage A (8*864 >= 6890)
#define LSTR 197     // LDS pair-row stride (uints)
#define MTB 32       // batches per block

typedef float f4 __attribute__((ext_vector_type(4)));
typedef float f32x4 __attribute__((ext_vector_type(4)));
typedef short bf16x8 __attribute__((ext_vector_type(8)));
typedef unsigned short ushort8 __attribute__((ext_vector_type(8)));

// ws layout (bytes):
//   Abuf  ushort[512][224]    @ 0         (229376)
//   Bbuf  ushort[20736][224]  @ 229376    (9289728)  end 9519104
//   Amd   ushort[512][16][32] @ 9519104   (524288)   end 10043392
//   part  float[24][8][33]    @ 10043392  (25344)    end 10068736
//   Wb    ushort[6912][32]    @ 10068736  (442368)   end 10511104

__device__ __forceinline__ unsigned short bf16_rne(float x) {
  union { float f; unsigned u; } c; c.f = x;
  unsigned r = c.u + 0x7fffu + ((c.u >> 16) & 1u);
  return (unsigned short)(r >> 16);
}
__device__ __forceinline__ float bf16lo_f(unsigned u) {
  union { unsigned u; float f; } c; c.u = u << 16; return c.f;
}
__device__ __forceinline__ float bf16hi_f(unsigned u) {
  union { unsigned u; float f; } c; c.u = u & 0xFFFF0000u; return c.f;
}

// ---------------- K0: partial JS reduction, grid (24, 8) ----------------
__global__ void k_jregA(const float* __restrict__ Jreg, const float* __restrict__ vtemp,
                        const float* __restrict__ sdirs, float* __restrict__ partial) {
  int j = blockIdx.x, bz = blockIdx.y;
  int tid = threadIdx.x;
  float acc[33];
#pragma unroll
  for (int i = 0; i < 33; ++i) acc[i] = 0.f;
  int v0 = bz * JCH;
  int v1 = v0 + JCH; if (v1 > NV) v1 = NV;
  for (int v = v0 + tid; v < v1; v += 256) {
    float w = Jreg[(size_t)j * NV + v];
    const float* vt = vtemp + (size_t)v * 3;
    acc[0] += w * vt[0]; acc[1] += w * vt[1]; acc[2] += w * vt[2];
    const float* sdv = sdirs + (size_t)v * 30;
#pragma unroll
    for (int t = 0; t < 30; ++t) acc[3 + t] += w * sdv[t];
  }
#pragma unroll
  for (int i = 0; i < 33; ++i) {
    float a = acc[i];
#pragma unroll
    for (int s = 32; s > 0; s >>= 1) a += __shfl_xor(a, s, 64);
    acc[i] = a;
  }
  __shared__ float red[4][34];
  int lane = tid & 63, wv = tid >> 6;
  if (lane == 0) {
#pragma unroll
    for (int i = 0; i < 33; ++i) red[wv][i] = acc[i];
  }
  __syncthreads();
  if (tid < 33) {
    float s = red[0][tid] + red[1][tid] + red[2][tid] + red[3][tid];
    partial[((size_t)j * 8 + bz) * 33 + tid] = s;
  }
}

// ---------------- K1: fused B/W prep ----------------
__global__ void k_prep(const float* __restrict__ pdirs, const float* __restrict__ sdirs,
                       const float* __restrict__ wgt,
                       unsigned short* __restrict__ Bbuf, unsigned short* __restrict__ Wb) {
  int idx = blockIdx.x * 256 + threadIdx.x;  // NCOLP*28 + NVP16*4 = 608256 = 2376*256
  if (idx < NCOLP * 28) {
    int n = idx / 28, k8 = idx % 28;
    int kbase = k8 * 8;
    ushort8 o;
#pragma unroll
    for (int e = 0; e < 8; ++e) {
      int k = kbase + e;
      float v = 0.f;
      if (n < NCOL) {
        if (k < 207) v = pdirs[(size_t)n * 207 + k];
        else if (k < 217) v = sdirs[(size_t)n * 10 + (k - 207)];
      }
      o[e] = bf16_rne(v);
    }
    *(ushort8*)(Bbuf + (size_t)n * KK + kbase) = o;
  } else {
    int widx = idx - NCOLP * 28;
    int v = widx >> 2, q = widx & 3;
    ushort8 o = {0, 0, 0, 0, 0, 0, 0, 0};
    if (v < NV && q < 3) {
#pragma unroll
      for (int e = 0; e < 8; ++e) o[e] = bf16_rne(wgt[(size_t)v * 24 + q * 8 + e]);
    }
    *(ushort8*)(Wb + (size_t)v * 32 + q * 8) = o;
  }
}

// ---------------- K2: per-batch joints, rodrigues, chain, Abuf+Amd ----------------
__global__ void k_batch(const float* __restrict__ pose, const float* __restrict__ beta,
                        const int* __restrict__ parent, const float* __restrict__ partial,
                        unsigned short* __restrict__ Abuf, unsigned short* __restrict__ Amd) {
  int b = blockIdx.x;
  int j = threadIdx.x;  // 64 threads
  __shared__ float jl[NJ][3];
  __shared__ float gl[NJ][16];

  {
    ushort8 z = {0, 0, 0, 0, 0, 0, 0, 0};
    *(ushort8*)(Amd + (size_t)b * 512 + j * 8) = z;
  }

  float bt[10];
#pragma unroll
  for (int t = 0; t < 10; ++t) bt[t] = beta[b * 10 + t];

  float R[9];
  float Jj[3] = {0.f, 0.f, 0.f};
  if (j < NJ) {
    float js[33];
#pragma unroll
    for (int q = 0; q < 33; ++q) js[q] = 0.f;
#pragma unroll
    for (int bz = 0; bz < 8; ++bz) {
      const float* pp = partial + ((size_t)j * 8 + bz) * 33;
#pragma unroll
      for (int q = 0; q < 33; ++q) js[q] += pp[q];
    }
#pragma unroll
    for (int c = 0; c < 3; ++c) {
      float a = js[c];
#pragma unroll
      for (int t = 0; t < 10; ++t) a += js[3 + c * 10 + t] * bt[t];
      Jj[c] = a;
      jl[j][c] = a;
    }
    float rx = pose[b * 72 + j * 3 + 0];
    float ry = pose[b * 72 + j * 3 + 1];
    float rz = pose[b * 72 + j * 3 + 2];
    float theta = sqrtf(rx * rx + ry * ry + rz * rz) + 1e-8f;
    float inv = 1.f / theta;
    float ax = rx * inv, ay = ry * inv, az = rz * inv;
    float c = cosf(theta), s = sinf(theta), oc = 1.f - c;
    R[0] = c + oc * ax * ax;      R[1] = oc * ax * ay - s * az; R[2] = oc * ax * az + s * ay;
    R[3] = oc * ax * ay + s * az; R[4] = c + oc * ay * ay;      R[5] = oc * ay * az - s * ax;
    R[6] = oc * ax * az - s * ay; R[7] = oc * ay * az + s * ax; R[8] = c + oc * az * az;
  }
  __syncthreads();

  if (j >= 1 && j < NJ) {
    unsigned short* lr = Abuf + b * KK + (j - 1) * 9;
#pragma unroll
    for (int k = 0; k < 9; ++k)
      lr[k] = bf16_rne(R[k] - ((k == 0 || k == 4 || k == 8) ? 1.f : 0.f));
  }
  if (j >= 32 && j < 42) Abuf[b * KK + 207 + (j - 32)] = bf16_rne(bt[j - 32]);
  if (j >= 42 && j < 49) Abuf[b * KK + 207 + (j - 32)] = 0;

  if (j < NJ) {
    int par = (j == 0) ? 0 : parent[j - 1];
#pragma unroll
    for (int r = 0; r < 3; ++r) {
      gl[j][r * 4 + 0] = R[r * 3 + 0];
      gl[j][r * 4 + 1] = R[r * 3 + 1];
      gl[j][r * 4 + 2] = R[r * 3 + 2];
      gl[j][r * 4 + 3] = (j == 0) ? Jj[r] : Jj[r] - jl[par][r];
    }
  }
  __syncthreads();

  if (j < NJ) {
    int a[12];
    int n = 0, cur = j;
    while (cur != 0 && n < 12) { a[n++] = cur; cur = parent[cur - 1]; }
    float G[12];
#pragma unroll
    for (int r = 0; r < 3; ++r)
#pragma unroll
      for (int cc = 0; cc < 4; ++cc) G[r * 4 + cc] = gl[0][r * 4 + cc];
    for (int i = n - 1; i >= 0; --i) {
      const float* L = gl[a[i]];
      float C[12];
#pragma unroll
      for (int r = 0; r < 3; ++r) {
#pragma unroll
        for (int cc = 0; cc < 4; ++cc) {
          float sacc = (cc == 3) ? G[r * 4 + 3] : 0.f;
#pragma unroll
          for (int k = 0; k < 3; ++k) sacc += G[r * 4 + k] * L[k * 4 + cc];
          C[r * 4 + cc] = sacc;
        }
      }
#pragma unroll
      for (int k = 0; k < 12; ++k) G[k] = C[k];
    }
    float Aval[12];
#pragma unroll
    for (int r = 0; r < 3; ++r) {
      Aval[r * 4 + 0] = G[r * 4 + 0];
      Aval[r * 4 + 1] = G[r * 4 + 1];
      Aval[r * 4 + 2] = G[r * 4 + 2];
      Aval[r * 4 + 3] = G[r * 4 + 3] -
                        (G[r * 4 + 0] * jl[j][0] + G[r * 4 + 1] * jl[j][1] + G[r * 4 + 2] * jl[j][2]);
    }
#pragma unroll
    for (int r = 0; r < 3; ++r)
#pragma unroll
      for (int cc = 0; cc < 4; ++cc)
        Amd[(size_t)b * 512 + (r * 4 + cc) * 32 + j] = bf16_rne(Aval[r * 4 + cc]);
  }
}

// ---------------- K3: fused pose-blend GEMM + MFMA skinning ----------------
// grid (108, 16), 256 threads. Tile: 192 cols (=64 verts) x 32 batches.
// Phase 1: vp(bf16-pair packed) -> LDS [16 pairs][LSTR].
// Phase 2: per wave 16 verts x 32 batches: T = Amd x W via MFMA, apply vp, store out.
__launch_bounds__(256)
__global__ void k_gemmskin(const unsigned short* __restrict__ Abuf,
                           const unsigned short* __restrict__ Bbuf,
                           const float* __restrict__ vtemp,
                           const unsigned short* __restrict__ Amd,
                           const unsigned short* __restrict__ Wb,
                           float* __restrict__ out) {
  __shared__ unsigned vp[(MTB / 2) * LSTR];  // 12608 B

  int tid = threadIdx.x;
  int wid = tid >> 6, lane = tid & 63;
  int lo = lane & 15, hi = lane >> 4;
  int n0 = blockIdx.x * 192;
  int bb0 = blockIdx.y * MTB;

  // ---- Phase 1: GEMM, 3 strips of 16 cols per wave ----
#pragma unroll
  for (int s = 0; s < 3; ++s) {
    int cb = wid * 48 + s * 16;
    const unsigned short* brow = Bbuf + (size_t)(n0 + cb + lo) * KK + hi * 8;
    bf16x8 Bf[7];
#pragma unroll
    for (int kc = 0; kc < 7; ++kc) Bf[kc] = *(const bf16x8*)(brow + kc * 32);
    int gc = n0 + cb + lo;
    float vt = (gc < NCOL) ? vtemp[gc] : 0.f;
#pragma unroll
    for (int mt = 0; mt < MTB / 16; ++mt) {
      const unsigned short* arow = Abuf + (size_t)(bb0 + mt * 16 + lo) * KK + hi * 8;
      f32x4 acc = {vt, vt, vt, vt};
#pragma unroll
      for (int kc = 0; kc < 7; ++kc) {
        bf16x8 Af = *(const bf16x8*)(arow + kc * 32);
        acc = __builtin_amdgcn_mfma_f32_16x16x32_bf16(Af, Bf[kc], acc, 0, 0, 0);
      }
#pragma unroll
      for (int rp = 0; rp < 2; ++rp) {
        unsigned pr = (unsigned)bf16_rne(acc[2 * rp]) |
                      ((unsigned)bf16_rne(acc[2 * rp + 1]) << 16);
        vp[(mt * 8 + hi * 2 + rp) * LSTR + cb + lo] = pr;
      }
    }
  }
  __syncthreads();

  // ---- Phase 2: MFMA skinning ----
  int vloc = wid * 16 + lo;
  int vg = blockIdx.x * 64 + vloc;
  bool sok = (vg < NV) && (hi < 3);

  bf16x8 Wf = *(const bf16x8*)(Wb + (size_t)vg * 32 + hi * 8);

#pragma unroll 4
  for (int p = 0; p < MTB / 2; ++p) {
    int b0 = bb0 + 2 * p;
    bf16x8 Af0 = *(const bf16x8*)(Amd + (size_t)b0 * 512 + lo * 32 + hi * 8);
    bf16x8 Af1 = *(const bf16x8*)(Amd + ((size_t)b0 + 1) * 512 + lo * 32 + hi * 8);
    unsigned ux = vp[p * LSTR + 3 * vloc + 0];
    unsigned uy = vp[p * LSTR + 3 * vloc + 1];
    unsigned uz = vp[p * LSTR + 3 * vloc + 2];
    f32x4 z = {0.f, 0.f, 0.f, 0.f};
    f32x4 c0 = __builtin_amdgcn_mfma_f32_16x16x32_bf16(Af0, Wf, z, 0, 0, 0);
    f32x4 c1 = __builtin_amdgcn_mfma_f32_16x16x32_bf16(Af1, Wf, z, 0, 0, 0);
    float o0 = c0[0] * bf16lo_f(ux) + c0[1] * bf16lo_f(uy) + c0[2] * bf16lo_f(uz) + c0[3];
    float o1 = c1[0] * bf16hi_f(ux) + c1[1] * bf16hi_f(uy) + c1[2] * bf16hi_f(uz) + c1[3];
    if (sok) {
      out[((size_t)b0 * NV + vg) * 3 + hi] = o0;
      out[(((size_t)b0 + 1) * NV + vg) * 3 + hi] = o1;
    }
  }
}

extern "C" void kernel_launch(void* const* d_in, const int* in_sizes, int n_in,
                              void* d_out, int out_size, void* d_ws, size_t ws_size,
                              hipStream_t stream) {
  const float* pose   = (const float*)d_in[0];
  const float* beta   = (const float*)d_in[1];
  const float* vtemp  = (const float*)d_in[2];
  const float* sdirs  = (const float*)d_in[3];
  const float* pdirs  = (const float*)d_in[4];
  const float* Jreg   = (const float*)d_in[5];
  const float* wgt    = (const float*)d_in[6];
  const int*   parent = (const int*)d_in[7];
  float* out = (float*)d_out;

  char* wsb = (char*)d_ws;
  unsigned short* Abuf = (unsigned short*)wsb;
  unsigned short* Bbuf = (unsigned short*)(wsb + 229376);
  unsigned short* Amd  = (unsigned short*)(wsb + 9519104);
  float* part          = (float*)(wsb + 10043392);
  unsigned short* Wb   = (unsigned short*)(wsb + 10068736);

  hipLaunchKernelGGL(k_jregA, dim3(NJ, 8), dim3(256), 0, stream, Jreg, vtemp, sdirs, part);
  hipLaunchKernelGGL(k_prep, dim3((NCOLP * 28 + NVP16 * 4) / 256), dim3(256), 0, stream,
                     pdirs, sdirs, wgt, Bbuf, Wb);
  hipLaunchKernelGGL(k_batch, dim3(BATCH), dim3(64), 0, stream, pose, beta, parent, part,
                     Abuf, Amd);
  hipLaunchKernelGGL(k_gemmskin, dim3(NCOLP / 192, BATCH / MTB), dim3(256), 0, stream,
                     Abuf, Bbuf, vtemp, Amd, Wb, out);
}

// Round 10
// 61.152 us; speedup vs baseline: 4.4415x; 1.2407x over previous
//
#include <hip/hip_runtime.h>

#define NV 6890
#define NVP16 6912   // padded to 16
#define NJ 24
#define BATCH 512
#define NCOL 20670   // NV*3
#define NCOLP 20736  // 108*192 (also 1296*16)
#define KK 224       // 207 pose + 10 beta + 7 zero
#define JCH 864      // vert chunk for jreg stage A (8*864 >= 6890)
#define LSTR 197     // LDS pair-row stride (uints)
#define MTB 32       // batches per block

typedef float f4 __attribute__((ext_vector_type(4)));
typedef float f32x4 __attribute__((ext_vector_type(4)));
typedef short bf16x8 __attribute__((ext_vector_type(8)));
typedef unsigned short ushort8 __attribute__((ext_vector_type(8)));

// ws layout (bytes):
//   Abuf  ushort[512][224]        @ 0         (229376)
//   Bbuf  ushort[1296][7][512]    @ 229376    (9289728)  end 9519104   (fragment-major)
//   Amd   ushort[512][16][32]     @ 9519104   (524288)   end 10043392
//   part  float[24][8][33]        @ 10043392  (25344)    end 10068736
//   Wb    ushort[6912][32]        @ 10068736  (442368)   end 10511104

__device__ __forceinline__ unsigned short bf16_rne(float x) {
  union { float f; unsigned u; } c; c.f = x;
  unsigned r = c.u + 0x7fffu + ((c.u >> 16) & 1u);
  return (unsigned short)(r >> 16);
}
__device__ __forceinline__ float bf16lo_f(unsigned u) {
  union { unsigned u; float f; } c; c.u = u << 16; return c.f;
}
__device__ __forceinline__ float bf16hi_f(unsigned u) {
  union { unsigned u; float f; } c; c.u = u & 0xFFFF0000u; return c.f;
}

// ---------------- K0: fused {jregA partials | B/W prep} ----------------
// blocks [0,192): jregA partial reduction (j = bid>>3, bz = bid&7)
// blocks [192, 192+2376): Bbuf (fragment-major) + Wb prep
__global__ void k_pre(const float* __restrict__ Jreg, const float* __restrict__ vtemp,
                      const float* __restrict__ sdirs, const float* __restrict__ pdirs,
                      const float* __restrict__ wgt,
                      float* __restrict__ partial, unsigned short* __restrict__ Bbuf,
                      unsigned short* __restrict__ Wb) {
  int bid = blockIdx.x;
  int tid = threadIdx.x;
  if (bid < 192) {
    int j = bid >> 3, bz = bid & 7;
    float acc[33];
#pragma unroll
    for (int i = 0; i < 33; ++i) acc[i] = 0.f;
    int v0 = bz * JCH;
    int v1 = v0 + JCH; if (v1 > NV) v1 = NV;
    for (int v = v0 + tid; v < v1; v += 256) {
      float w = Jreg[(size_t)j * NV + v];
      const float* vt = vtemp + (size_t)v * 3;
      acc[0] += w * vt[0]; acc[1] += w * vt[1]; acc[2] += w * vt[2];
      const float* sdv = sdirs + (size_t)v * 30;
#pragma unroll
      for (int t = 0; t < 30; ++t) acc[3 + t] += w * sdv[t];
    }
#pragma unroll
    for (int i = 0; i < 33; ++i) {
      float a = acc[i];
#pragma unroll
      for (int s = 32; s > 0; s >>= 1) a += __shfl_xor(a, s, 64);
      acc[i] = a;
    }
    __shared__ float red[4][34];
    int lane = tid & 63, wv = tid >> 6;
    if (lane == 0) {
#pragma unroll
      for (int i = 0; i < 33; ++i) red[wv][i] = acc[i];
    }
    __syncthreads();
    if (tid < 33) {
      float s = red[0][tid] + red[1][tid] + red[2][tid] + red[3][tid];
      partial[((size_t)j * 8 + bz) * 33 + tid] = s;
    }
    return;
  }
  int idx = (bid - 192) * 256 + tid;  // NCOLP*28 + NVP16*4 = 608256 = 2376*256
  if (idx < NCOLP * 28) {
    int n = idx / 28, k8 = idx % 28;
    int kc = k8 >> 2, h = k8 & 3;   // k = k8*8 + e = kc*32 + h*8 + e
    ushort8 o;
#pragma unroll
    for (int e = 0; e < 8; ++e) {
      int k = k8 * 8 + e;
      float v = 0.f;
      if (n < NCOL) {
        if (k < 207) v = pdirs[(size_t)n * 207 + k];
        else if (k < 217) v = sdirs[(size_t)n * 10 + (k - 207)];
      }
      o[e] = bf16_rne(v);
    }
    // fragment-major: lane (h*16 + n%16) of tile n/16, chunk kc
    size_t dst = ((size_t)(n >> 4) * 7 + kc) * 512 + (size_t)(h * 16 + (n & 15)) * 8;
    *(ushort8*)(Bbuf + dst) = o;
  } else {
    int widx = idx - NCOLP * 28;
    int v = widx >> 2, q = widx & 3;
    ushort8 o = {0, 0, 0, 0, 0, 0, 0, 0};
    if (v < NV && q < 3) {
#pragma unroll
      for (int e = 0; e < 8; ++e) o[e] = bf16_rne(wgt[(size_t)v * 24 + q * 8 + e]);
    }
    *(ushort8*)(Wb + (size_t)v * 32 + q * 8) = o;
  }
}

// ---------------- K1: per-batch joints, rodrigues, chain, Abuf+Amd ----------------
__global__ void k_batch(const float* __restrict__ pose, const float* __restrict__ beta,
                        const int* __restrict__ parent, const float* __restrict__ partial,
                        unsigned short* __restrict__ Abuf, unsigned short* __restrict__ Amd) {
  int b = blockIdx.x;
  int j = threadIdx.x;  // 64 threads
  __shared__ float jl[NJ][3];
  __shared__ float gl[NJ][16];

  {
    ushort8 z = {0, 0, 0, 0, 0, 0, 0, 0};
    *(ushort8*)(Amd + (size_t)b * 512 + j * 8) = z;
  }

  float bt[10];
#pragma unroll
  for (int t = 0; t < 10; ++t) bt[t] = beta[b * 10 + t];

  float R[9];
  float Jj[3] = {0.f, 0.f, 0.f};
  if (j < NJ) {
    float js[33];
#pragma unroll
    for (int q = 0; q < 33; ++q) js[q] = 0.f;
#pragma unroll
    for (int bz = 0; bz < 8; ++bz) {
      const float* pp = partial + ((size_t)j * 8 + bz) * 33;
#pragma unroll
      for (int q = 0; q < 33; ++q) js[q] += pp[q];
    }
#pragma unroll
    for (int c = 0; c < 3; ++c) {
      float a = js[c];
#pragma unroll
      for (int t = 0; t < 10; ++t) a += js[3 + c * 10 + t] * bt[t];
      Jj[c] = a;
      jl[j][c] = a;
    }
    float rx = pose[b * 72 + j * 3 + 0];
    float ry = pose[b * 72 + j * 3 + 1];
    float rz = pose[b * 72 + j * 3 + 2];
    float theta = sqrtf(rx * rx + ry * ry + rz * rz) + 1e-8f;
    float inv = 1.f / theta;
    float ax = rx * inv, ay = ry * inv, az = rz * inv;
    float c = cosf(theta), s = sinf(theta), oc = 1.f - c;
    R[0] = c + oc * ax * ax;      R[1] = oc * ax * ay - s * az; R[2] = oc * ax * az + s * ay;
    R[3] = oc * ax * ay + s * az; R[4] = c + oc * ay * ay;      R[5] = oc * ay * az - s * ax;
    R[6] = oc * ax * az - s * ay; R[7] = oc * ay * az + s * ax; R[8] = c + oc * az * az;
  }
  __syncthreads();

  if (j >= 1 && j < NJ) {
    unsigned short* lr = Abuf + b * KK + (j - 1) * 9;
#pragma unroll
    for (int k = 0; k < 9; ++k)
      lr[k] = bf16_rne(R[k] - ((k == 0 || k == 4 || k == 8) ? 1.f : 0.f));
  }
  if (j >= 32 && j < 42) Abuf[b * KK + 207 + (j - 32)] = bf16_rne(bt[j - 32]);
  if (j >= 42 && j < 49) Abuf[b * KK + 207 + (j - 32)] = 0;

  if (j < NJ) {
    int par = (j == 0) ? 0 : parent[j - 1];
#pragma unroll
    for (int r = 0; r < 3; ++r) {
      gl[j][r * 4 + 0] = R[r * 3 + 0];
      gl[j][r * 4 + 1] = R[r * 3 + 1];
      gl[j][r * 4 + 2] = R[r * 3 + 2];
      gl[j][r * 4 + 3] = (j == 0) ? Jj[r] : Jj[r] - jl[par][r];
    }
  }
  __syncthreads();

  if (j < NJ) {
    int a[12];
    int n = 0, cur = j;
    while (cur != 0 && n < 12) { a[n++] = cur; cur = parent[cur - 1]; }
    float G[12];
#pragma unroll
    for (int r = 0; r < 3; ++r)
#pragma unroll
      for (int cc = 0; cc < 4; ++cc) G[r * 4 + cc] = gl[0][r * 4 + cc];
    for (int i = n - 1; i >= 0; --i) {
      const float* L = gl[a[i]];
      float C[12];
#pragma unroll
      for (int r = 0; r < 3; ++r) {
#pragma unroll
        for (int cc = 0; cc < 4; ++cc) {
          float sacc = (cc == 3) ? G[r * 4 + 3] : 0.f;
#pragma unroll
          for (int k = 0; k < 3; ++k) sacc += G[r * 4 + k] * L[k * 4 + cc];
          C[r * 4 + cc] = sacc;
        }
      }
#pragma unroll
      for (int k = 0; k < 12; ++k) G[k] = C[k];
    }
    float Aval[12];
#pragma unroll
    for (int r = 0; r < 3; ++r) {
      Aval[r * 4 + 0] = G[r * 4 + 0];
      Aval[r * 4 + 1] = G[r * 4 + 1];
      Aval[r * 4 + 2] = G[r * 4 + 2];
      Aval[r * 4 + 3] = G[r * 4 + 3] -
                        (G[r * 4 + 0] * jl[j][0] + G[r * 4 + 1] * jl[j][1] + G[r * 4 + 2] * jl[j][2]);
    }
#pragma unroll
    for (int r = 0; r < 3; ++r)
#pragma unroll
      for (int cc = 0; cc < 4; ++cc)
        Amd[(size_t)b * 512 + (r * 4 + cc) * 32 + j] = bf16_rne(Aval[r * 4 + cc]);
  }
}

// ---------------- K2: fused pose-blend GEMM + MFMA skinning ----------------
// 1D grid 1792 (pad of 112x16), XCD-bijective swizzle: xcd = bid&7 owns 14 bx values.
// Tile: 192 cols (=64 verts) x 32 batches.
__launch_bounds__(256, 4)
__global__ void k_gemmskin(const unsigned short* __restrict__ Abuf,
                           const unsigned short* __restrict__ Bbuf,
                           const float* __restrict__ vtemp,
                           const unsigned short* __restrict__ Amd,
                           const unsigned short* __restrict__ Wb,
                           float* __restrict__ out) {
  __shared__ unsigned vp[(MTB / 2) * LSTR];  // 12608 B

  int bid = blockIdx.x;
  int xcd = bid & 7, jj = bid >> 3;
  int bx = xcd * 14 + (jj % 14);
  int by = jj / 14;
  if (bx >= 108) return;

  int tid = threadIdx.x;
  int wid = tid >> 6, lane = tid & 63;
  int lo = lane & 15, hi = lane >> 4;
  int n0 = bx * 192;
  int bb0 = by * MTB;

  // ---- Phase 1: GEMM; A-fragments hoisted (strip-invariant) ----
  bf16x8 Af[2][7];
#pragma unroll
  for (int mt = 0; mt < 2; ++mt) {
    const unsigned short* arow = Abuf + (size_t)(bb0 + mt * 16 + lo) * KK + hi * 8;
#pragma unroll
    for (int kc = 0; kc < 7; ++kc)
      Af[mt][kc] = *(const bf16x8*)(arow + kc * 32);
  }

#pragma unroll
  for (int s = 0; s < 3; ++s) {
    int cb = wid * 48 + s * 16;
    // fragment-major B: one contiguous 1KB load per kc
    const unsigned short* btile = Bbuf + ((size_t)(bx * 12 + wid * 3 + s) * 7) * 512 + lane * 8;
    bf16x8 Bf[7];
#pragma unroll
    for (int kc = 0; kc < 7; ++kc) Bf[kc] = *(const bf16x8*)(btile + kc * 512);
    int gc = n0 + cb + lo;
    float vt = (gc < NCOL) ? vtemp[gc] : 0.f;
#pragma unroll
    for (int mt = 0; mt < 2; ++mt) {
      f32x4 acc = {vt, vt, vt, vt};
#pragma unroll
      for (int kc = 0; kc < 7; ++kc)
        acc = __builtin_amdgcn_mfma_f32_16x16x32_bf16(Af[mt][kc], Bf[kc], acc, 0, 0, 0);
#pragma unroll
      for (int rp = 0; rp < 2; ++rp) {
        unsigned pr = (unsigned)bf16_rne(acc[2 * rp]) |
                      ((unsigned)bf16_rne(acc[2 * rp + 1]) << 16);
        vp[(mt * 8 + hi * 2 + rp) * LSTR + cb + lo] = pr;
      }
    }
  }
  __syncthreads();

  // ---- Phase 2: MFMA skinning, 4 batch-pairs per group for MLP ----
  int vloc = wid * 16 + lo;
  int vg = bx * 64 + vloc;
  bool sok = (vg < NV) && (hi < 3);

  bf16x8 Wf = *(const bf16x8*)(Wb + (size_t)vg * 32 + hi * 8);

#pragma unroll
  for (int g = 0; g < 4; ++g) {
    bf16x8 A0[4], A1[4];
    unsigned ux[4], uy[4], uz[4];
#pragma unroll
    for (int q = 0; q < 4; ++q) {
      int p = g * 4 + q;
      int b0 = bb0 + 2 * p;
      A0[q] = *(const bf16x8*)(Amd + (size_t)b0 * 512 + lo * 32 + hi * 8);
      A1[q] = *(const bf16x8*)(Amd + ((size_t)b0 + 1) * 512 + lo * 32 + hi * 8);
      ux[q] = vp[p * LSTR + 3 * vloc + 0];
      uy[q] = vp[p * LSTR + 3 * vloc + 1];
      uz[q] = vp[p * LSTR + 3 * vloc + 2];
    }
#pragma unroll
    for (int q = 0; q < 4; ++q) {
      int b0 = bb0 + 2 * (g * 4 + q);
      f32x4 z = {0.f, 0.f, 0.f, 0.f};
      f32x4 c0 = __builtin_amdgcn_mfma_f32_16x16x32_bf16(A0[q], Wf, z, 0, 0, 0);
      f32x4 c1 = __builtin_amdgcn_mfma_f32_16x16x32_bf16(A1[q], Wf, z, 0, 0, 0);
      float o0 = c0[0] * bf16lo_f(ux[q]) + c0[1] * bf16lo_f(uy[q]) + c0[2] * bf16lo_f(uz[q]) + c0[3];
      float o1 = c1[0] * bf16hi_f(ux[q]) + c1[1] * bf16hi_f(uy[q]) + c1[2] * bf16hi_f(uz[q]) + c1[3];
      if (sok) {
        out[((size_t)b0 * NV + vg) * 3 + hi] = o0;
        out[(((size_t)b0 + 1) * NV + vg) * 3 + hi] = o1;
      }
    }
  }
}

extern "C" void kernel_launch(void* const* d_in, const int* in_sizes, int n_in,
                              void* d_out, int out_size, void* d_ws, size_t ws_size,
                              hipStream_t stream) {
  const float* pose   = (const float*)d_in[0];
  const float* beta   = (const float*)d_in[1];
  const float* vtemp  = (const float*)d_in[2];
  const float* sdirs  = (const float*)d_in[3];
  const float* pdirs  = (const float*)d_in[4];
  const float* Jreg   = (const float*)d_in[5];
  const float* wgt    = (const float*)d_in[6];
  const int*   parent = (const int*)d_in[7];
  float* out = (float*)d_out;

  char* wsb = (char*)d_ws;
  unsigned short* Abuf = (unsigned short*)wsb;
  unsigned short* Bbuf = (unsigned short*)(wsb + 229376);
  unsigned short* Amd  = (unsigned short*)(wsb + 9519104);
  float* part          = (float*)(wsb + 10043392);
  unsigned short* Wb   = (unsigned short*)(wsb + 10068736);

  hipLaunchKernelGGL(k_pre, dim3(192 + (NCOLP * 28 + NVP16 * 4) / 256), dim3(256), 0, stream,
                     Jreg, vtemp, sdirs, pdirs, wgt, part, Bbuf, Wb);
  hipLaunchKernelGGL(k_batch, dim3(BATCH), dim3(64), 0, stream, pose, beta, parent, part,
                     Abuf, Amd);
  hipLaunchKernelGGL(k_gemmskin, dim3(1792), dim3(256), 0, stream,
                     Abuf, Bbuf, vtemp, Amd, Wb, out);
}

// Round 11
// 57.218 us; speedup vs baseline: 4.7469x; 1.0687x over previous
//
#include <hip/hip_runtime.h>

#define NV 6890
#define NVP16 6912   // padded to 16
#define NJ 24
#define BATCH 512
#define NCOL 20670   // NV*3
#define NCOLP 20736  // 108*192 (also 1296*16)
#define KK 224       // 207 pose + 10 beta + 7 zero
#define JCH 864      // vert chunk for jreg stage A (8*864 >= 6890)
#define LSTR 197     // LDS pair-row stride (uints)
#define MTB 32       // batches per block

typedef float f4 __attribute__((ext_vector_type(4)));
typedef float f32x4 __attribute__((ext_vector_type(4)));
typedef short bf16x8 __attribute__((ext_vector_type(8)));
typedef unsigned short ushort8 __attribute__((ext_vector_type(8)));

// ws layout (bytes):
//   Abuf  ushort[512][224]        @ 0         (229376)
//   Bbuf  ushort[1296][7][512]    @ 229376    (9289728)  end 9519104   (fragment-major)
//   Amd   ushort[512][16][32]     @ 9519104   (524288)   end 10043392
//   part  float[24][8][33]        @ 10043392  (25344)    end 10068736
//   Wb    ushort[6912][32]        @ 10068736  (442368)   end 10511104

__device__ __forceinline__ unsigned short bf16_rne(float x) {
  union { float f; unsigned u; } c; c.f = x;
  unsigned r = c.u + 0x7fffu + ((c.u >> 16) & 1u);
  return (unsigned short)(r >> 16);
}
__device__ __forceinline__ float bf16lo_f(unsigned u) {
  union { unsigned u; float f; } c; c.u = u << 16; return c.f;
}
__device__ __forceinline__ float bf16hi_f(unsigned u) {
  union { unsigned u; float f; } c; c.u = u & 0xFFFF0000u; return c.f;
}

// ---------------- K0: fused {jregA partials | B/W prep} ----------------
__global__ void k_pre(const float* __restrict__ Jreg, const float* __restrict__ vtemp,
                      const float* __restrict__ sdirs, const float* __restrict__ pdirs,
                      const float* __restrict__ wgt,
                      float* __restrict__ partial, unsigned short* __restrict__ Bbuf,
                      unsigned short* __restrict__ Wb) {
  int bid = blockIdx.x;
  int tid = threadIdx.x;
  if (bid < 192) {
    int j = bid >> 3, bz = bid & 7;
    float acc[33];
#pragma unroll
    for (int i = 0; i < 33; ++i) acc[i] = 0.f;
    int v0 = bz * JCH;
    int v1 = v0 + JCH; if (v1 > NV) v1 = NV;
    for (int v = v0 + tid; v < v1; v += 256) {
      float w = Jreg[(size_t)j * NV + v];
      const float* vt = vtemp + (size_t)v * 3;
      acc[0] += w * vt[0]; acc[1] += w * vt[1]; acc[2] += w * vt[2];
      const float* sdv = sdirs + (size_t)v * 30;
#pragma unroll
      for (int t = 0; t < 30; ++t) acc[3 + t] += w * sdv[t];
    }
#pragma unroll
    for (int i = 0; i < 33; ++i) {
      float a = acc[i];
#pragma unroll
      for (int s = 32; s > 0; s >>= 1) a += __shfl_xor(a, s, 64);
      acc[i] = a;
    }
    __shared__ float red[4][34];
    int lane = tid & 63, wv = tid >> 6;
    if (lane == 0) {
#pragma unroll
      for (int i = 0; i < 33; ++i) red[wv][i] = acc[i];
    }
    __syncthreads();
    if (tid < 33) {
      float s = red[0][tid] + red[1][tid] + red[2][tid] + red[3][tid];
      partial[((size_t)j * 8 + bz) * 33 + tid] = s;
    }
    return;
  }
  int idx = (bid - 192) * 256 + tid;  // NCOLP*28 + NVP16*4 = 608256 = 2376*256
  if (idx < NCOLP * 28) {
    int n = idx / 28, k8 = idx % 28;
    int kc = k8 >> 2, h = k8 & 3;
    ushort8 o;
#pragma unroll
    for (int e = 0; e < 8; ++e) {
      int k = k8 * 8 + e;
      float v = 0.f;
      if (n < NCOL) {
        if (k < 207) v = pdirs[(size_t)n * 207 + k];
        else if (k < 217) v = sdirs[(size_t)n * 10 + (k - 207)];
      }
      o[e] = bf16_rne(v);
    }
    size_t dst = ((size_t)(n >> 4) * 7 + kc) * 512 + (size_t)(h * 16 + (n & 15)) * 8;
    *(ushort8*)(Bbuf + dst) = o;
  } else {
    int widx = idx - NCOLP * 28;
    int v = widx >> 2, q = widx & 3;
    ushort8 o = {0, 0, 0, 0, 0, 0, 0, 0};
    if (v < NV && q < 3) {
#pragma unroll
      for (int e = 0; e < 8; ++e) o[e] = bf16_rne(wgt[(size_t)v * 24 + q * 8 + e]);
    }
    *(ushort8*)(Wb + (size_t)v * 32 + q * 8) = o;
  }
}

// ---------------- K1: joints/rodrigues/chain — 4 batches per 256-thread block ----------------
__global__ void k_batch(const float* __restrict__ pose, const float* __restrict__ beta,
                        const int* __restrict__ parent, const float* __restrict__ partial,
                        unsigned short* __restrict__ Abuf, unsigned short* __restrict__ Amd) {
  int tid = threadIdx.x;
  int g = tid >> 6;      // sub-batch 0..3
  int j = tid & 63;
  int b = blockIdx.x * 4 + g;
  __shared__ float JS[NJ][33];
  __shared__ float jl[4][NJ][3];
  __shared__ float gl[4][NJ][16];

  // Amd zero-fill: 4 batches x 512 ushorts = 256 x ushort8
  {
    ushort8 z = {0, 0, 0, 0, 0, 0, 0, 0};
    *(ushort8*)(Amd + (size_t)blockIdx.x * 2048 + tid * 8) = z;
  }

  // JS summed once per block (cooperative)
  for (int i = tid; i < NJ * 33; i += 256) {
    int jj = i / 33, q = i % 33;
    float s = 0.f;
#pragma unroll
    for (int bz = 0; bz < 8; ++bz) s += partial[((size_t)jj * 8 + bz) * 33 + q];
    JS[jj][q] = s;
  }
  __syncthreads();

  float bt[10];
#pragma unroll
  for (int t = 0; t < 10; ++t) bt[t] = beta[b * 10 + t];

  float R[9];
  float Jj[3] = {0.f, 0.f, 0.f};
  if (j < NJ) {
#pragma unroll
    for (int c = 0; c < 3; ++c) {
      float a = JS[j][c];
#pragma unroll
      for (int t = 0; t < 10; ++t) a += JS[j][3 + c * 10 + t] * bt[t];
      Jj[c] = a;
      jl[g][j][c] = a;
    }
    float rx = pose[b * 72 + j * 3 + 0];
    float ry = pose[b * 72 + j * 3 + 1];
    float rz = pose[b * 72 + j * 3 + 2];
    float theta = sqrtf(rx * rx + ry * ry + rz * rz) + 1e-8f;
    float inv = 1.f / theta;
    float ax = rx * inv, ay = ry * inv, az = rz * inv;
    float c = cosf(theta), s = sinf(theta), oc = 1.f - c;
    R[0] = c + oc * ax * ax;      R[1] = oc * ax * ay - s * az; R[2] = oc * ax * az + s * ay;
    R[3] = oc * ax * ay + s * az; R[4] = c + oc * ay * ay;      R[5] = oc * ay * az - s * ax;
    R[6] = oc * ax * az - s * ay; R[7] = oc * ay * az + s * ax; R[8] = c + oc * az * az;
  }
  __syncthreads();

  if (j >= 1 && j < NJ) {
    unsigned short* lr = Abuf + b * KK + (j - 1) * 9;
#pragma unroll
    for (int k = 0; k < 9; ++k)
      lr[k] = bf16_rne(R[k] - ((k == 0 || k == 4 || k == 8) ? 1.f : 0.f));
  }
  if (j >= 32 && j < 42) Abuf[b * KK + 207 + (j - 32)] = bf16_rne(bt[j - 32]);
  if (j >= 42 && j < 49) Abuf[b * KK + 207 + (j - 32)] = 0;

  if (j < NJ) {
    int par = (j == 0) ? 0 : parent[j - 1];
#pragma unroll
    for (int r = 0; r < 3; ++r) {
      gl[g][j][r * 4 + 0] = R[r * 3 + 0];
      gl[g][j][r * 4 + 1] = R[r * 3 + 1];
      gl[g][j][r * 4 + 2] = R[r * 3 + 2];
      gl[g][j][r * 4 + 3] = (j == 0) ? Jj[r] : Jj[r] - jl[g][par][r];
    }
  }
  __syncthreads();

  if (j < NJ) {
    int a[12];
    int n = 0, cur = j;
    while (cur != 0 && n < 12) { a[n++] = cur; cur = parent[cur - 1]; }
    float G[12];
#pragma unroll
    for (int r = 0; r < 3; ++r)
#pragma unroll
      for (int cc = 0; cc < 4; ++cc) G[r * 4 + cc] = gl[g][0][r * 4 + cc];
    for (int i = n - 1; i >= 0; --i) {
      const float* L = gl[g][a[i]];
      float C[12];
#pragma unroll
      for (int r = 0; r < 3; ++r) {
#pragma unroll
        for (int cc = 0; cc < 4; ++cc) {
          float sacc = (cc == 3) ? G[r * 4 + 3] : 0.f;
#pragma unroll
          for (int k = 0; k < 3; ++k) sacc += G[r * 4 + k] * L[k * 4 + cc];
          C[r * 4 + cc] = sacc;
        }
      }
#pragma unroll
      for (int k = 0; k < 12; ++k) G[k] = C[k];
    }
    float Aval[12];
#pragma unroll
    for (int r = 0; r < 3; ++r) {
      Aval[r * 4 + 0] = G[r * 4 + 0];
      Aval[r * 4 + 1] = G[r * 4 + 1];
      Aval[r * 4 + 2] = G[r * 4 + 2];
      Aval[r * 4 + 3] = G[r * 4 + 3] -
                        (G[r * 4 + 0] * jl[g][j][0] + G[r * 4 + 1] * jl[g][j][1] +
                         G[r * 4 + 2] * jl[g][j][2]);
    }
#pragma unroll
    for (int r = 0; r < 3; ++r)
#pragma unroll
      for (int cc = 0; cc < 4; ++cc)
        Amd[(size_t)b * 512 + (r * 4 + cc) * 32 + j] = bf16_rne(Aval[r * 4 + cc]);
  }
}

// ---------------- K2: fused pose-blend GEMM + MFMA skinning ----------------
// grid 1728 exact; bijective XCD swizzle: lin=(bid&7)*216+(bid>>3); bx=lin>>4; by=lin&15.
__launch_bounds__(256, 4)
__global__ void k_gemmskin(const unsigned short* __restrict__ Abuf,
                           const unsigned short* __restrict__ Bbuf,
                           const float* __restrict__ vtemp,
                           const unsigned short* __restrict__ Amd,
                           const unsigned short* __restrict__ Wb,
                           float* __restrict__ out) {
  __shared__ unsigned vp[(MTB / 2) * LSTR];  // 12608 B

  int bid = blockIdx.x;
  int lin = (bid & 7) * 216 + (bid >> 3);
  int bx = lin >> 4;
  int by = lin & 15;

  int tid = threadIdx.x;
  int wid = tid >> 6, lane = tid & 63;
  int lo = lane & 15, hi = lane >> 4;
  int n0 = bx * 192;
  int bb0 = by * MTB;

  // ---- Phase 1: GEMM; A-fragments hoisted (strip-invariant) ----
  bf16x8 Af[2][7];
#pragma unroll
  for (int mt = 0; mt < 2; ++mt) {
    const unsigned short* arow = Abuf + (size_t)(bb0 + mt * 16 + lo) * KK + hi * 8;
#pragma unroll
    for (int kc = 0; kc < 7; ++kc)
      Af[mt][kc] = *(const bf16x8*)(arow + kc * 32);
  }

#pragma unroll
  for (int s = 0; s < 3; ++s) {
    int cb = wid * 48 + s * 16;
    const unsigned short* btile = Bbuf + ((size_t)(bx * 12 + wid * 3 + s) * 7) * 512 + lane * 8;
    bf16x8 Bf[7];
#pragma unroll
    for (int kc = 0; kc < 7; ++kc) Bf[kc] = *(const bf16x8*)(btile + kc * 512);
    int gc = n0 + cb + lo;
    float vt = (gc < NCOL) ? vtemp[gc] : 0.f;
#pragma unroll
    for (int mt = 0; mt < 2; ++mt) {
      f32x4 acc = {vt, vt, vt, vt};
#pragma unroll
      for (int kc = 0; kc < 7; ++kc)
        acc = __builtin_amdgcn_mfma_f32_16x16x32_bf16(Af[mt][kc], Bf[kc], acc, 0, 0, 0);
#pragma unroll
      for (int rp = 0; rp < 2; ++rp) {
        unsigned pr = (unsigned)bf16_rne(acc[2 * rp]) |
                      ((unsigned)bf16_rne(acc[2 * rp + 1]) << 16);
        vp[(mt * 8 + hi * 2 + rp) * LSTR + cb + lo] = pr;
      }
    }
  }

  // ---- barrier-shadowed prefetch: Wf + phase-2 group 0 A tiles ----
  int vloc = wid * 16 + lo;
  int vg = bx * 64 + vloc;
  bool sok = (vg < NV) && (hi < 3);

  bf16x8 Wf = *(const bf16x8*)(Wb + (size_t)vg * 32 + hi * 8);
  bf16x8 A0p[4], A1p[4];
#pragma unroll
  for (int q = 0; q < 4; ++q) {
    int b0 = bb0 + 2 * q;
    A0p[q] = *(const bf16x8*)(Amd + (size_t)b0 * 512 + lo * 32 + hi * 8);
    A1p[q] = *(const bf16x8*)(Amd + ((size_t)b0 + 1) * 512 + lo * 32 + hi * 8);
  }
  __syncthreads();

  // ---- Phase 2: MFMA skinning, 4 batch-pairs per group ----
#pragma unroll
  for (int g = 0; g < 4; ++g) {
    bf16x8 A0[4], A1[4];
    unsigned ux[4], uy[4], uz[4];
#pragma unroll
    for (int q = 0; q < 4; ++q) {
      int p = g * 4 + q;
      if (g == 0) {
        A0[q] = A0p[q];
        A1[q] = A1p[q];
      } else {
        int b0 = bb0 + 2 * p;
        A0[q] = *(const bf16x8*)(Amd + (size_t)b0 * 512 + lo * 32 + hi * 8);
        A1[q] = *(const bf16x8*)(Amd + ((size_t)b0 + 1) * 512 + lo * 32 + hi * 8);
      }
      ux[q] = vp[p * LSTR + 3 * vloc + 0];
      uy[q] = vp[p * LSTR + 3 * vloc + 1];
      uz[q] = vp[p * LSTR + 3 * vloc + 2];
    }
#pragma unroll
    for (int q = 0; q < 4; ++q) {
      int b0 = bb0 + 2 * (g * 4 + q);
      f32x4 z = {0.f, 0.f, 0.f, 0.f};
      f32x4 c0 = __builtin_amdgcn_mfma_f32_16x16x32_bf16(A0[q], Wf, z, 0, 0, 0);
      f32x4 c1 = __builtin_amdgcn_mfma_f32_16x16x32_bf16(A1[q], Wf, z, 0, 0, 0);
      float o0 = c0[0] * bf16lo_f(ux[q]) + c0[1] * bf16lo_f(uy[q]) + c0[2] * bf16lo_f(uz[q]) + c0[3];
      float o1 = c1[0] * bf16hi_f(ux[q]) + c1[1] * bf16hi_f(uy[q]) + c1[2] * bf16hi_f(uz[q]) + c1[3];
      if (sok) {
        out[((size_t)b0 * NV + vg) * 3 + hi] = o0;
        out[(((size_t)b0 + 1) * NV + vg) * 3 + hi] = o1;
      }
    }
  }
}

extern "C" void kernel_launch(void* const* d_in, const int* in_sizes, int n_in,
                              void* d_out, int out_size, void* d_ws, size_t ws_size,
                              hipStream_t stream) {
  const float* pose   = (const float*)d_in[0];
  const float* beta   = (const float*)d_in[1];
  const float* vtemp  = (const float*)d_in[2];
  const float* sdirs  = (const float*)d_in[3];
  const float* pdirs  = (const float*)d_in[4];
  const float* Jreg   = (const float*)d_in[5];
  const float* wgt    = (const float*)d_in[6];
  const int*   parent = (const int*)d_in[7];
  float* out = (float*)d_out;

  char* wsb = (char*)d_ws;
  unsigned short* Abuf = (unsigned short*)wsb;
  unsigned short* Bbuf = (unsigned short*)(wsb + 229376);
  unsigned short* Amd  = (unsigned short*)(wsb + 9519104);
  float* part          = (float*)(wsb + 10043392);
  unsigned short* Wb   = (unsigned short*)(wsb + 10068736);

  hipLaunchKernelGGL(k_pre, dim3(192 + (NCOLP * 28 + NVP16 * 4) / 256), dim3(256), 0, stream,
                     Jreg, vtemp, sdirs, pdirs, wgt, part, Bbuf, Wb);
  hipLaunchKernelGGL(k_batch, dim3(BATCH / 4), dim3(256), 0, stream, pose, beta, parent, part,
                     Abuf, Amd);
  hipLaunchKernelGGL(k_gemmskin, dim3(1728), dim3(256), 0, stream,
                     Abuf, Bbuf, vtemp, Amd, Wb, out);
}